// Round 12
// baseline (418.017 us; speedup 1.0000x reference)
//
#include <hip/hip_runtime.h>
#include <math.h>
#include <stdint.h>

// Problem constants (B=2, S=1024, H=2048, E=16, K=4, CAP=768)
#define NTOK 2048
#define HDIM 2048
#define HHALF 1024
#define EDIM 16
#define CAPV 768
#define TOPK 4
#define GK 2048        // K is 2048 for every GEMM in this problem

typedef __bf16 bf16x8 __attribute__((ext_vector_type(8)));
typedef __bf16 bf16x4 __attribute__((ext_vector_type(4)));
typedef float f32x4 __attribute__((ext_vector_type(4)));
typedef float f32x16 __attribute__((ext_vector_type(16)));

// =====================================================================
// Stage-A GEMM: round-10 read-ahead 2-barrier schedule, with the MFMA
// shape switched 16x16x32 -> 32x32x16 (m06/m119: 2382-2495 TF vs 2075;
// half the MFMA instruction count, same LDS bytes).
// Tile 256x256, BK=32, 512 thr = 8 waves (2M x 4N), per-wave 128x64 =
// 4(m) x 2(n) fragments of 32x32.  LDS: 2 bufs x 4 arrays x [256][32]
// bf16 = 128 KB.
// Operand layout 32x32x16: row = lane&31, k = (lane>>5)*8 + j
// (direct analog of the verified 16x16x32 layout used since round 2).
// C/D layout [m74/m101]: col = lane&31, row=(reg&3)+8*(reg>>2)+4*(lane>>5).
// Groups per K-tile (ks0/ks1 = k-halves 0..15 / 16..31):
//  g0: stage Ah',Wh' | read ah(ks0),bh0,bl0 | MFMA8 ah*bh0
//      gate vmcnt(4) -> Al(t) landed | BARRIER
//  g1: stage Wl',Al' | read al(ks0)         | MFMA8 ah*bl0
//  g2: read ah(ks1),bh1                     | MFMA8 al*bh0
//  g3: read al(ks1),bl1                     | MFMA8 ah*bh1
//  g4:                                        MFMA8 ah*bl1 ; MFMA8 al*bh1
//      gate vmcnt(2) -> Ah',Wh',Wl' landed | BARRIER   [exit: Al'x2]
// Same per-wave vmcnt FIFO discipline as round 10 (never drains
// mid-loop; every read barrier-separated from its gate).
// Swizzle rule #21: linear LDS dest + inverse-swizzled global source +
// swizzled ds_read offsets; chunk ^= (row>>1)&3 within 64B rows.
// =====================================================================

struct GJobA {
  const __bf16 *Ah, *Al, *Wh, *Wl;   // A [M][K] split; W^T [N][K] split
  const float* bias;
  float* Cf; __bf16 *Ch, *Cl;
  int relu, N, blk0;
};
struct GJobsA { GJobA j[6]; };

#define BKA 32
#define NTA 64   // 2048 / 32 K-tiles

#define BARR __builtin_amdgcn_s_barrier()
#define SCHED0 __builtin_amdgcn_sched_barrier(0)
#define PRIO1 __builtin_amdgcn_s_setprio(1)
#define PRIO0 __builtin_amdgcn_s_setprio(0)

__global__ __launch_bounds__(512, 2) void gemm_phased(GJobsA P) {
  __shared__ __align__(16) __bf16 lds[2][4][256 * BKA];  // 128 KB

  const int tid = threadIdx.x;
  const int wid = tid >> 6, lane = tid & 63;
  const int lane31 = lane & 31, khalf = lane >> 5;

  // job select from flat block id
  const int bid = blockIdx.x;
  int ji = 0;
#pragma unroll
  for (int k = 1; k < 6; ++k)
    if (bid >= P.j[k].blk0) ji = k;
  const GJobA J = P.j[ji];
  const int local = bid - J.blk0;
  const int nbx = J.N >> 8;                 // 8 or 4 (power of two)
  const int bx = local & (nbx - 1);
  const int by = local / nbx;
  const int m0 = by * 256, n0 = bx * 256;

  const int wr = wid >> 2, wc = wid & 3;    // 2(M) x 4(N) waves -> 128x64 each

  // staging: per thread 2 chunks (16B) per array; source pre-swizzled
  int srow[2], soff[2];
#pragma unroll
  for (int h = 0; h < 2; ++h) {
    int s = tid + h * 512;
    int row = s >> 2;
    srow[h] = row;
    soff[h] = ((s & 3) ^ ((row >> 1) & 3)) * 8;
  }

  // fragment ds_read byte offsets (swizzled), constant across tiles
  // offA[ks][mi], offB[ks][ni]; chunk = ks*2 + khalf, XOR row swizzle
  int offA[2][4], offB[2][2];
#pragma unroll
  for (int ks = 0; ks < 2; ++ks) {
#pragma unroll
    for (int mi = 0; mi < 4; ++mi) {
      int ra = wr * 128 + mi * 32 + lane31;
      offA[ks][mi] = ra * 64 + (((ks * 2 + khalf) ^ ((ra >> 1) & 3)) << 4);
    }
#pragma unroll
    for (int ni = 0; ni < 2; ++ni) {
      int rb = wc * 64 + ni * 32 + lane31;
      offB[ks][ni] = rb * 64 + (((ks * 2 + khalf) ^ ((rb >> 1) & 3)) << 4);
    }
  }

#define STAGE2(gptr, grow0, k1, larr)                                          \
  { _Pragma("unroll") for (int h = 0; h < 2; ++h) {                            \
      const __bf16* _src =                                                     \
          (gptr) + (size_t)((grow0) + srow[h]) * GK + (k1) + soff[h];          \
      __builtin_amdgcn_global_load_lds(                                        \
          (const __attribute__((address_space(1))) uint32_t*)_src,             \
          (__attribute__((address_space(3))) uint32_t*)((larr) +               \
              (wid * 64 + h * 512) * 8), 16, 0, 0); } }

#define DSR_A(dst, base, ks)                                                   \
  { _Pragma("unroll") for (int i = 0; i < 4; ++i)                              \
      dst[i] = *(const bf16x8*)((base) + offA[ks][i]); }
#define DSR_B(dst, base, ks)                                                   \
  { _Pragma("unroll") for (int i = 0; i < 2; ++i)                              \
      dst[i] = *(const bf16x8*)((base) + offB[ks][i]); }
#define MFMA8(af, bf)                                                          \
  { _Pragma("unroll") for (int mi = 0; mi < 4; ++mi)                           \
    _Pragma("unroll") for (int ni = 0; ni < 2; ++ni)                           \
      acc[mi][ni] = __builtin_amdgcn_mfma_f32_32x32x16_bf16(                   \
          af[mi], bf[ni], acc[mi][ni], 0, 0, 0); }

  f32x16 acc[4][2];
#pragma unroll
  for (int i = 0; i < 4; ++i)
#pragma unroll
    for (int j = 0; j < 2; ++j)
#pragma unroll
      for (int r = 0; r < 16; ++r) acc[i][j][r] = 0.0f;

  // prologue: stage tile 0 in FIFO order Ah,Wh,Wl,Al; gate all but Al
  STAGE2(J.Ah, m0, 0, lds[0][0]);
  STAGE2(J.Wh, n0, 0, lds[0][2]);
  STAGE2(J.Wl, n0, 0, lds[0][3]);
  STAGE2(J.Al, m0, 0, lds[0][1]);
  asm volatile("s_waitcnt vmcnt(2)" ::: "memory");   // Ah,Wh,Wl landed
  BARR;
  SCHED0;

  bf16x8 ah[4], al[4], bh0[2], bl0[2], bh1[2], bl1[2];

  for (int t = 0; t < NTA; ++t) {
    const int cur = t & 1, nxt = cur ^ 1;
    const bool hasNext = (t + 1 < NTA);
    const int k1 = (t + 1) * BKA;
    const char* cAh = (const char*)lds[cur][0];
    const char* cAl = (const char*)lds[cur][1];
    const char* cBh = (const char*)lds[cur][2];
    const char* cBl = (const char*)lds[cur][3];

    // ---- g0: stage Ah',Wh' | read ah(ks0),bh0,bl0 | MFMA ah*bh0 ----
    if (hasNext) {
      STAGE2(J.Ah, m0, k1, lds[nxt][0]);
      STAGE2(J.Wh, n0, k1, lds[nxt][2]);
    }
    DSR_A(ah, cAh, 0);
    DSR_B(bh0, cBh, 0);
    DSR_B(bl0, cBl, 0);
    PRIO1; MFMA8(ah, bh0); PRIO0;
    if (hasNext) { asm volatile("s_waitcnt vmcnt(4)" ::: "memory"); }
    else         { asm volatile("s_waitcnt vmcnt(0)" ::: "memory"); }
    SCHED0;
    BARR;
    SCHED0;
    // ---- g1: stage Wl',Al' | read al(ks0) | MFMA ah*bl0 ----
    if (hasNext) {
      STAGE2(J.Wl, n0, k1, lds[nxt][3]);
      STAGE2(J.Al, m0, k1, lds[nxt][1]);
    }
    DSR_A(al, cAl, 0);
    PRIO1; MFMA8(ah, bl0); PRIO0;
    // ---- g2: read ah(ks1),bh1 | MFMA al*bh0 ----
    DSR_A(ah, cAh, 1);
    DSR_B(bh1, cBh, 1);
    PRIO1; MFMA8(al, bh0); PRIO0;
    // ---- g3: read al(ks1),bl1 | MFMA ah*bh1 ----
    DSR_A(al, cAl, 1);
    DSR_B(bl1, cBl, 1);
    PRIO1; MFMA8(ah, bh1); PRIO0;
    // ---- g4: MFMA ah*bl1 ; MFMA al*bh1 ----
    PRIO1; MFMA8(ah, bl1); MFMA8(al, bh1); PRIO0;
    if (hasNext) {
      asm volatile("s_waitcnt vmcnt(2)" ::: "memory");  // Ah',Wh',Wl' landed
      SCHED0;
      BARR;
      SCHED0;
    }
  }

  // epilogue: 32x32 C/D layout col=lane&31, row=(r&3)+8*(r>>2)+4*(lane>>5)
#pragma unroll
  for (int mi = 0; mi < 4; ++mi)
#pragma unroll
    for (int ni = 0; ni < 2; ++ni) {
      int col = n0 + wc * 64 + ni * 32 + lane31;
      float bv = J.bias[col];
      f32x16 v = acc[mi][ni];
#pragma unroll
      for (int r = 0; r < 16; ++r) {
        int row = m0 + wr * 128 + mi * 32 + (r & 3) + 8 * (r >> 2) + 4 * khalf;
        float x = v[r] + bv;
        if (J.relu) x = fmaxf(x, 0.0f);
        size_t o = (size_t)row * J.N + col;
        if (J.Cf) J.Cf[o] = x;
        if (J.Ch) {
          __bf16 hh = (__bf16)x;
          J.Ch[o] = hh;
          J.Cl[o] = (__bf16)(x - (float)hh);
        }
      }
    }
#undef STAGE2
#undef DSR_A
#undef DSR_B
#undef MFMA8
}

// =====================================================================
// Stage-B' GEMM: proven 128x128 / BK=64 / 4-wave kernel, + kLen for
// split-K (pointers pre-offset by the host; partials, relu deferred).
// =====================================================================
#define BKT 64

struct GJob {
  const __bf16* Ah; const __bf16* Al;
  const __bf16* Wh; const __bf16* Wl;
  const float* bias;
  float* Cf;
  __bf16* Ch; __bf16* Cl;
  int relu; int N; int blk0; int kLen;
};
struct GJobs { GJob j[4]; int njobs; };

__device__ __forceinline__ void stage_tile(const __bf16* __restrict__ g,
                                           int grow0, int k0,
                                           __bf16* lbase, int wid, int lane) {
  int r_in = lane >> 3;
  int swz_elems = ((lane & 7) ^ r_in) << 3;
#pragma unroll
  for (int i = 0; i < 4; ++i) {
    int row0 = wid * 32 + i * 8;
    const __bf16* src = g + (size_t)(grow0 + row0 + r_in) * GK + k0 + swz_elems;
    __builtin_amdgcn_global_load_lds(
        (const __attribute__((address_space(1))) uint32_t*)src,
        (__attribute__((address_space(3))) uint32_t*)(lbase + row0 * BKT),
        16, 0, 0);
  }
}

__global__ __launch_bounds__(256) void gemm_split(GJobs P) {
  __shared__ __align__(16) __bf16 lds[4 * 128 * BKT];
  __bf16* ldsAh = lds;
  __bf16* ldsAl = lds + 8192;
  __bf16* ldsBh = lds + 16384;
  __bf16* ldsBl = lds + 24576;
  const char* cAh = (const char*)ldsAh;
  const char* cAl = (const char*)ldsAl;
  const char* cBh = (const char*)ldsBh;
  const char* cBl = (const char*)ldsBl;

  const int bid = blockIdx.x;
  int ji = 0;
#pragma unroll
  for (int k = 1; k < 4; ++k)
    if (k < P.njobs && bid >= P.j[k].blk0) ji = k;
  const GJob J = P.j[ji];
  const int local = bid - J.blk0;
  const int nbx = J.N >> 7;
  const int bx = local & (nbx - 1);
  const int by = local / nbx;
  const int m0 = by * 128;
  const int n0 = bx * 128;

  const int tid = threadIdx.x;
  const int wid = tid >> 6;
  const int lane = tid & 63;
  const int lane15 = lane & 15;
  const int c0 = lane >> 4;
  const int wr = wid >> 1;
  const int wc = wid & 1;

  int offA[4][2], offB[4][2];
#pragma unroll
  for (int i = 0; i < 4; ++i) {
    int ra = wr * 64 + i * 16 + lane15;
    int rb = wc * 64 + i * 16 + lane15;
#pragma unroll
    for (int ks = 0; ks < 2; ++ks) {
      offA[i][ks] = ra * 128 + (((ks * 4 + c0) ^ (ra & 7)) << 4);
      offB[i][ks] = rb * 128 + (((ks * 4 + c0) ^ (rb & 7)) << 4);
    }
  }

  f32x4 acc[4][4];
#pragma unroll
  for (int i = 0; i < 4; ++i)
#pragma unroll
    for (int j = 0; j < 4; ++j) acc[i][j] = (f32x4){0.f, 0.f, 0.f, 0.f};

  for (int k0 = 0; k0 < J.kLen; k0 += BKT) {
    stage_tile(J.Ah, m0, k0, ldsAh, wid, lane);
    stage_tile(J.Al, m0, k0, ldsAl, wid, lane);
    stage_tile(J.Wh, n0, k0, ldsBh, wid, lane);
    stage_tile(J.Wl, n0, k0, ldsBl, wid, lane);
    __syncthreads();
#pragma unroll
    for (int ks = 0; ks < 2; ++ks) {
      bf16x8 ah[4], al[4], bh[4], bl[4];
#pragma unroll
      for (int i = 0; i < 4; ++i) {
        ah[i] = *(const bf16x8*)(cAh + offA[i][ks]);
        al[i] = *(const bf16x8*)(cAl + offA[i][ks]);
        bh[i] = *(const bf16x8*)(cBh + offB[i][ks]);
        bl[i] = *(const bf16x8*)(cBl + offB[i][ks]);
      }
#pragma unroll
      for (int mi = 0; mi < 4; ++mi)
#pragma unroll
        for (int ni = 0; ni < 4; ++ni) {
          acc[mi][ni] = __builtin_amdgcn_mfma_f32_16x16x32_bf16(
              ah[mi], bh[ni], acc[mi][ni], 0, 0, 0);
          acc[mi][ni] = __builtin_amdgcn_mfma_f32_16x16x32_bf16(
              ah[mi], bl[ni], acc[mi][ni], 0, 0, 0);
          acc[mi][ni] = __builtin_amdgcn_mfma_f32_16x16x32_bf16(
              al[mi], bh[ni], acc[mi][ni], 0, 0, 0);
        }
    }
    __syncthreads();
  }

#pragma unroll
  for (int mi = 0; mi < 4; ++mi) {
#pragma unroll
    for (int ni = 0; ni < 4; ++ni) {
      int col = n0 + wc * 64 + ni * 16 + lane15;
      float bv = J.bias[col];
      f32x4 v = acc[mi][ni];
#pragma unroll
      for (int j = 0; j < 4; ++j) {
        int row = m0 + wr * 64 + mi * 16 + c0 * 4 + j;
        float x = v[j] + bv;
        if (J.relu) x = fmaxf(x, 0.0f);
        size_t o = (size_t)row * J.N + col;
        if (J.Cf) J.Cf[o] = x;
        if (J.Ch) {
          __bf16 hh = (__bf16)x;
          J.Ch[o] = hh;
          J.Cl[o] = (__bf16)(x - (float)hh);
        }
      }
    }
  }
}

// =====================================================================
// prep: fused preprocessing — 4 elementwise splits + 6 transpose-splits
// + 2 prebias reductions, one dispatch via flat block-range job table.
// =====================================================================
struct SJob { const float* in; __bf16* h; __bf16* l; };
struct TJob { const float* W; __bf16* Th; __bf16* Tl; int Nd; };
struct PrepArgs {
  SJob s[4];
  TJob t[6];
  const float* pb2;
  const float* pW1a; const float* pb1a; float* pva;
  const float* pW1b; const float* pb1b; float* pvb;
};

__global__ __launch_bounds__(256) void prep(PrepArgs P) {
  __shared__ float tbuf[32][33];
  const int bid = blockIdx.x;
  const int tid = threadIdx.x;
  if (bid < 16384) {
    SJob J = P.s[bid >> 12];
    int i = (bid & 4095) * 256 + tid;
    float4 v = ((const float4*)J.in)[i];
    bf16x4 hv, lv;
    hv.x = (__bf16)v.x; lv.x = (__bf16)(v.x - (float)hv.x);
    hv.y = (__bf16)v.y; lv.y = (__bf16)(v.y - (float)hv.y);
    hv.z = (__bf16)v.z; lv.z = (__bf16)(v.z - (float)hv.z);
    hv.w = (__bf16)v.w; lv.w = (__bf16)(v.w - (float)hv.w);
    ((bf16x4*)J.h)[i] = hv;
    ((bf16x4*)J.l)[i] = lv;
  } else if (bid < 32768) {
    int local = bid - 16384;
    int ji, ln;
    if (local < 4096)      { ji = 0; ln = local; }
    else if (local < 8192) { ji = 1; ln = local - 4096; }
    else { ji = 2 + ((local - 8192) >> 11); ln = (local - 8192) & 2047; }
    TJob J = P.t[ji];
    int full = (J.Nd == HDIM);
    int n0 = (full ? (ln & 63) : (ln & 31)) * 32;
    int k0 = (full ? (ln >> 6) : (ln >> 5)) * 32;
    int tx = tid & 31, ty = tid >> 5;
#pragma unroll
    for (int i = 0; i < 4; ++i) {
      int kk = ty + i * 8;
      tbuf[kk][tx] = J.W[(size_t)(k0 + kk) * J.Nd + n0 + tx];
    }
    __syncthreads();
#pragma unroll
    for (int i = 0; i < 4; ++i) {
      int nn = ty + i * 8;
      float v = tbuf[tx][nn];
      __bf16 hh = (__bf16)v;
      size_t o = (size_t)(n0 + nn) * GK + k0 + tx;
      J.Th[o] = hh;
      J.Tl[o] = (__bf16)(v - (float)hh);
    }
  } else {
    int local = bid - 32768;                 // 64 blocks: 2 sides x 8 k x 4 n
    int side = local >> 5; int r = local & 31;
    const float* W1 = side ? P.pW1b : P.pW1a;
    const float* b1 = side ? P.pb1b : P.pb1a;
    float* v = side ? P.pvb : P.pva;
    int n = (r & 3) * 256 + tid;
    int k0 = (r >> 2) * 256;
    float acc = (k0 == 0) ? b1[n] : 0.0f;
#pragma unroll 8
    for (int k = 0; k < 256; ++k)
      acc = fmaf(P.pb2[k0 + k], W1[(size_t)(k0 + k) * HHALF + n], acc);
    atomicAdd(&v[n], acc);
  }
}

// ---------------- Skinny logits, 5 routers batched ----------------
struct LJob { const float* Y; const float* Y2; const float* W2;
              const float* b2; float* L; int K; int relu; };
struct LJobs { LJob j[5]; };
__global__ __launch_bounds__(256) void logits_kernel(LJobs P) {
  const LJob J = P.j[blockIdx.x >> 8];
  const int blk = blockIdx.x & 255;
  const int tid = threadIdx.x;
  const int wid = tid >> 6, lane = tid & 63;
  const int e = lane & 15;
  const int kq = lane >> 4;
  const int tok0 = blk * 8 + wid * 2;
  const float* y0 = J.Y + (size_t)tok0 * J.K;
  const float* y1 = y0 + J.K;
  const float* z0 = J.Y2 + (size_t)tok0 * J.K;
  const float* z1 = z0 + J.K;
  const int KQ = J.K >> 2;
  const int kbase = kq * KQ;
  float a0 = 0.f, a1 = 0.f;
  if (J.relu) {
#pragma unroll 8
    for (int k = 0; k < KQ; ++k) {
      int kk = kbase + k;
      float w = J.W2[(size_t)kk * EDIM + e];
      float v0 = fmaxf(y0[kk] + z0[kk], 0.0f);
      float v1 = fmaxf(y1[kk] + z1[kk], 0.0f);
      a0 = fmaf(v0, w, a0);
      a1 = fmaf(v1, w, a1);
    }
  } else {
#pragma unroll 8
    for (int k = 0; k < KQ; ++k) {
      int kk = kbase + k;
      float w = J.W2[(size_t)kk * EDIM + e];
      a0 = fmaf(y0[kk], w, a0);
      a1 = fmaf(y1[kk], w, a1);
    }
  }
  a0 += __shfl_xor(a0, 16); a0 += __shfl_xor(a0, 32);
  a1 += __shfl_xor(a1, 16); a1 += __shfl_xor(a1, 32);
  if (lane < 16) {
    float b = J.b2[e];
    J.L[(size_t)tok0 * EDIM + e] = a0 + b;
    J.L[(size_t)(tok0 + 1) * EDIM + e] = a1 + b;
  }
}

// ---------------- Router finalize ----------------
__device__ __forceinline__ void softmax16(const float* __restrict__ L, float* __restrict__ p) {
  float v[16];
  *(float4*)&v[0]  = *(const float4*)&L[0];
  *(float4*)&v[4]  = *(const float4*)&L[4];
  *(float4*)&v[8]  = *(const float4*)&L[8];
  *(float4*)&v[12] = *(const float4*)&L[12];
  float m = v[0];
#pragma unroll
  for (int e = 1; e < 16; ++e) m = fmaxf(m, v[e]);
  float s = 0.0f;
#pragma unroll
  for (int e = 0; e < 16; ++e) { v[e] = expf(v[e] - m); s += v[e]; }
  float inv = 1.0f / s;
#pragma unroll
  for (int e = 0; e < 16; ++e) p[e] = v[e] * inv;
}

__global__ __launch_bounds__(256) void finalize_kernel(
    const float* __restrict__ Lg, const float* __restrict__ Lsi,
    const float* __restrict__ Lsg, const float* __restrict__ Lsc,
    const float* __restrict__ Lsb,
    float* __restrict__ dispatch, float* __restrict__ combine,
    float* __restrict__ router_probs, float* __restrict__ mean_acc) {
  __shared__ float sm[EDIM];
  int tid = threadIdx.x;
  if (tid < EDIM) sm[tid] = 0.0f;
  __syncthreads();

  int tok = blockIdx.x * 256 + tid;
  float pg[16], ps[16], tmp[16], r[16];
  softmax16(Lg + (size_t)tok * EDIM, pg);
  softmax16(Lsi + (size_t)tok * EDIM, ps);
  softmax16(Lsg + (size_t)tok * EDIM, tmp);
#pragma unroll
  for (int e = 0; e < 16; ++e) ps[e] += tmp[e];
  softmax16(Lsc + (size_t)tok * EDIM, tmp);
#pragma unroll
  for (int e = 0; e < 16; ++e) ps[e] += tmp[e];
  softmax16(Lsb + (size_t)tok * EDIM, tmp);
#pragma unroll
  for (int e = 0; e < 16; ++e) ps[e] += tmp[e];

#pragma unroll
  for (int e = 0; e < 16; ++e) {
    float s = ps[e] * 0.5f;
    r[e] = 0.7f * pg[e] + 0.3f * s;
  }

#pragma unroll
  for (int e = 0; e < 16; e += 4) {
    float4 o = {r[e], r[e + 1], r[e + 2], r[e + 3]};
    *(float4*)&router_probs[(size_t)tok * EDIM + e] = o;
  }

#pragma unroll
  for (int e = 0; e < 16; ++e) atomicAdd(&sm[e], r[e]);

  bool used[16];
#pragma unroll
  for (int e = 0; e < 16; ++e) used[e] = false;
  int idx[TOPK];
  float tp[TOPK];
  float tsum = 0.0f;
#pragma unroll
  for (int j = 0; j < TOPK; ++j) {
    float best = -1.0f;
    int bi = 0;
#pragma unroll
    for (int e = 0; e < 16; ++e) {
      bool take = (!used[e]) && (r[e] > best);
      best = take ? r[e] : best;
      bi = take ? e : bi;
    }
    used[bi] = true;
    idx[j] = bi;
    tp[j] = best;
    tsum += best;
  }
  float invt = 1.0f / tsum;
#pragma unroll
  for (int j = 0; j < TOPK; ++j) {
    size_t off = ((size_t)tok * EDIM + idx[j]) * CAPV;
    dispatch[off] = 1.0f;
    combine[off] = tp[j] * invt;
  }

  __syncthreads();
  if (tid < EDIM) atomicAdd(&mean_acc[tid], sm[tid]);
}

__global__ void aux_kernel(const float* __restrict__ mean_acc, float* __restrict__ out_aux) {
  if (threadIdx.x == 0 && blockIdx.x == 0) {
    float s = 0.0f;
    for (int e = 0; e < EDIM; ++e) {
      float m = mean_acc[e] * (1.0f / (float)NTOK);
      s += m * logf(m * (float)EDIM + 1e-9f);
    }
    *out_aux = s;
  }
}

// ---------------- launch ----------------
#define MBYTE (1ull << 20)

extern "C" void kernel_launch(void* const* d_in, const int* in_sizes, int n_in,
                              void* d_out, int out_size, void* d_ws, size_t ws_size,
                              hipStream_t stream) {
  const float* X    = (const float*)d_in[0];
  const float* IMG  = (const float*)d_in[1];
  const float* GEN  = (const float*)d_in[2];
  const float* g_w1 = (const float*)d_in[3];
  const float* g_b1 = (const float*)d_in[4];
  const float* g_w2 = (const float*)d_in[5];
  const float* g_b2 = (const float*)d_in[6];
  const float* m_w1 = (const float*)d_in[7];
  const float* m_b1 = (const float*)d_in[8];
  const float* m_w2 = (const float*)d_in[9];
  const float* m_b2 = (const float*)d_in[10];
  const float* si_w1 = (const float*)d_in[11];
  const float* si_b1 = (const float*)d_in[12];
  const float* si_w2 = (const float*)d_in[13];
  const float* si_b2 = (const float*)d_in[14];
  const float* sg_w1 = (const float*)d_in[15];
  const float* sg_b1 = (const float*)d_in[16];
  const float* sg_w2 = (const float*)d_in[17];
  const float* sg_b2 = (const float*)d_in[18];
  const float* sc_w1 = (const float*)d_in[19];
  const float* sc_b1 = (const float*)d_in[20];
  const float* sc_w2 = (const float*)d_in[21];
  const float* sc_b2 = (const float*)d_in[22];
  const float* sb_w1 = (const float*)d_in[23];
  const float* sb_b1 = (const float*)d_in[24];
  const float* sb_w2 = (const float*)d_in[25];
  const float* sb_b2 = (const float*)d_in[26];

  char* wsb = (char*)d_ws;
  __bf16* Xh    = (__bf16*)(wsb + 0 * MBYTE);
  __bf16* Xl    = (__bf16*)(wsb + 8 * MBYTE);
  __bf16* IMGh  = (__bf16*)(wsb + 16 * MBYTE);
  __bf16* IMGl  = (__bf16*)(wsb + 24 * MBYTE);
  __bf16* GENh  = (__bf16*)(wsb + 32 * MBYTE);
  __bf16* GENl  = (__bf16*)(wsb + 40 * MBYTE);
  __bf16* M2h   = (__bf16*)(wsb + 48 * MBYTE);   // m_w2 elementwise split
  __bf16* M2l   = (__bf16*)(wsb + 56 * MBYTE);
  __bf16* Wm1h  = (__bf16*)(wsb + 64 * MBYTE);
  __bf16* Wm1l  = (__bf16*)(wsb + 72 * MBYTE);
  __bf16* Wg1h  = (__bf16*)(wsb + 80 * MBYTE);
  __bf16* Wg1l  = (__bf16*)(wsb + 88 * MBYTE);
  __bf16* Wsch  = (__bf16*)(wsb + 96 * MBYTE);
  __bf16* Wscl  = (__bf16*)(wsb + 100 * MBYTE);
  __bf16* Wsbh  = (__bf16*)(wsb + 104 * MBYTE);
  __bf16* Wsbl  = (__bf16*)(wsb + 108 * MBYTE);
  __bf16* Wsih  = (__bf16*)(wsb + 112 * MBYTE);
  __bf16* Wsil  = (__bf16*)(wsb + 116 * MBYTE);
  __bf16* Wsgh  = (__bf16*)(wsb + 120 * MBYTE);
  __bf16* Wsgl  = (__bf16*)(wsb + 124 * MBYTE);
  __bf16* H1h   = (__bf16*)(wsb + 128 * MBYTE);
  __bf16* H1l   = (__bf16*)(wsb + 136 * MBYTE);
  __bf16* WPsch = (__bf16*)(wsb + 144 * MBYTE);  // (m_w2@sc_w1)^T split [1024][2048]
  __bf16* WPscl = (__bf16*)(wsb + 148 * MBYTE);
  __bf16* WPsbh = (__bf16*)(wsb + 152 * MBYTE);
  __bf16* WPsbl = (__bf16*)(wsb + 156 * MBYTE);
  float*  YG    = (float*)(wsb + 160 * MBYTE);
  float*  YSI   = (float*)(wsb + 176 * MBYTE);
  float*  YSG   = (float*)(wsb + 184 * MBYTE);
  float*  YSCp0 = (float*)(wsb + 192 * MBYTE);   // split-K partials (bias in p0)
  float*  YSCp1 = (float*)(wsb + 200 * MBYTE);
  float*  YSBp0 = (float*)(wsb + 208 * MBYTE);
  float*  YSBp1 = (float*)(wsb + 216 * MBYTE);
  float* L0 = (float*)(wsb + 224 * MBYTE);
  float* L1 = L0 + NTOK * EDIM;
  float* L2 = L1 + NTOK * EDIM;
  float* L3 = L2 + NTOK * EDIM;
  float* L4 = L3 + NTOK * EDIM;
  float* meanp = L4 + NTOK * EDIM;
  float* zbias = meanp + EDIM;         // 2048 zeros (bias for W'/kh1 jobs)
  float* vsc = zbias + GK;
  float* vsb = vsc + HHALF;

  float* dispatch = (float*)d_out;
  float* combine = dispatch + (size_t)NTOK * EDIM * CAPV;
  float* rp = combine + (size_t)NTOK * EDIM * CAPV;
  float* aux = rp + (size_t)NTOK * EDIM;

  hipMemsetAsync(d_out, 0, (size_t)out_size * sizeof(float), stream);
  hipMemsetAsync(meanp, 0, (EDIM + GK + 2 * HHALF) * sizeof(float), stream);

  dim3 blk(256);

  // 1) fused prep: splits + transpose-splits + prebias (one dispatch)
  {
    PrepArgs p;
    p.s[0] = {X, Xh, Xl};
    p.s[1] = {IMG, IMGh, IMGl};
    p.s[2] = {GEN, GENh, GENl};
    p.s[3] = {m_w2, M2h, M2l};
    p.t[0] = {m_w1, Wm1h, Wm1l, HDIM};
    p.t[1] = {g_w1, Wg1h, Wg1l, HDIM};
    p.t[2] = {sc_w1, Wsch, Wscl, HHALF};
    p.t[3] = {sb_w1, Wsbh, Wsbl, HHALF};
    p.t[4] = {si_w1, Wsih, Wsil, HHALF};
    p.t[5] = {sg_w1, Wsgh, Wsgl, HHALF};
    p.pb2 = m_b2;
    p.pW1a = sc_w1; p.pb1a = sc_b1; p.pva = vsc;
    p.pW1b = sb_w1; p.pb1b = sb_b1; p.pvb = vsb;
    prep<<<32832, blk, 0, stream>>>(p);
  }

  // 2) GEMM stage A: 6 independent jobs, exactly 256 blocks (32x32 MFMA)
  {
    GJobsA g;
    g.j[0] = {Xh, Xl, Wm1h, Wm1l, m_b1, nullptr, H1h, H1l, 1, HDIM, 0};      // 64
    g.j[1] = {Xh, Xl, Wg1h, Wg1l, g_b1, YG, nullptr, nullptr, 1, HDIM, 64};  // 64
    g.j[2] = {IMGh, IMGl, Wsih, Wsil, si_b1, YSI, nullptr, nullptr, 1, HHALF, 128}; // 32
    g.j[3] = {GENh, GENl, Wsgh, Wsgl, sg_b1, YSG, nullptr, nullptr, 1, HHALF, 160}; // 32
    g.j[4] = {Wsch, Wscl, M2h, M2l, zbias, nullptr, WPsch, WPscl, 0, HDIM, 192};    // 32 (M=1024)
    g.j[5] = {Wsbh, Wsbl, M2h, M2l, zbias, nullptr, WPsbh, WPsbl, 0, HDIM, 224};    // 32 (M=1024)
    gemm_phased<<<256, dim3(512), 0, stream>>>(g);
  }

  // 3) GEMM stage B': split-K=2 partials (relu deferred to logits), 512 blocks
  {
    GJobs g;
    g.j[0] = {H1h, H1l, WPsch, WPscl, vsc, YSCp0, nullptr, nullptr, 0, HHALF, 0, 1024};
    g.j[1] = {H1h + 1024, H1l + 1024, WPsch + 1024, WPscl + 1024, zbias, YSCp1,
              nullptr, nullptr, 0, HHALF, 128, 1024};
    g.j[2] = {H1h, H1l, WPsbh, WPsbl, vsb, YSBp0, nullptr, nullptr, 0, HHALF, 256, 1024};
    g.j[3] = {H1h + 1024, H1l + 1024, WPsbh + 1024, WPsbl + 1024, zbias, YSBp1,
              nullptr, nullptr, 0, HHALF, 384, 1024};
    g.njobs = 4;
    gemm_split<<<512, blk, 0, stream>>>(g);
  }

  // 4) batched logits (all 5 routers; sc/sb sum partials + relu)
  {
    LJobs l;
    l.j[0] = {YG, YG, g_w2, g_b2, L0, HDIM, 0};
    l.j[1] = {YSI, YSI, si_w2, si_b2, L1, HHALF, 0};
    l.j[2] = {YSG, YSG, sg_w2, sg_b2, L2, HHALF, 0};
    l.j[3] = {YSCp0, YSCp1, sc_w2, sc_b2, L3, HHALF, 1};
    l.j[4] = {YSBp0, YSBp1, sb_w2, sb_b2, L4, HHALF, 1};
    logits_kernel<<<5 * 256, blk, 0, stream>>>(l);
  }

  // 5) finalize + aux
  finalize_kernel<<<NTOK / 256, blk, 0, stream>>>(L0, L1, L2, L3, L4,
                                                  dispatch, combine, rp, meanp);
  aux_kernel<<<1, 64, 0, stream>>>(meanp, aux);
}

// Round 13
// 405.046 us; speedup vs baseline: 1.0320x; 1.0320x over previous
//
#include <hip/hip_runtime.h>
#include <math.h>
#include <stdint.h>

// Problem constants (B=2, S=1024, H=2048, E=16, K=4, CAP=768)
#define NTOK 2048
#define HDIM 2048
#define HHALF 1024
#define EDIM 16
#define CAPV 768
#define TOPK 4
#define GK 2048        // K is 2048 for every GEMM in this problem

typedef __bf16 bf16x8 __attribute__((ext_vector_type(8)));
typedef __bf16 bf16x4 __attribute__((ext_vector_type(4)));
typedef float f32x4 __attribute__((ext_vector_type(4)));

// =====================================================================
// Stage-A GEMM: round-10 read-ahead 2-barrier schedule (16x16x32 MFMA —
// the measured equilibrium: 171us / MfmaUtil 53% / 0 bank conflicts.
// 32x32x16 regressed: 64B rows give 32-lane reads only 4 chunk slots ->
// inherent 4-way conflict, +1.26e7 SQ_LDS_BANK_CONFLICT, 186us).
// Tile 256x256, BK=32, 512 thr = 8 waves (2M x 4N), per-wave 128x64.
// LDS: 2 bufs x 4 arrays (Ah,Al,Bh,Bl) x [256][32]bf16 = 128 KB.
// Per-wave vmcnt FIFO (2 loads per STAGE2), steady state:
//   g0: stage Ah',Wh' | read ah0,bh,bl | MFMA ah0*bh
//       gate vmcnt(4) -> Al(t) landed | BARRIER
//   g1: stage Wl',Al' | read al0 | MFMA ah0*bl
//   g2: read ah1 | MFMA al0*bh
//   g3: read al1 | MFMA ah1*bh
//   g4: MFMA ah1*bl ; MFMA al1*bh
//       gate vmcnt(2) -> Ah',Wh',Wl' landed | BARRIER   [exit: Al'x2]
// Swizzle rule #21: linear LDS dest + inverse-swizzled global source +
// swizzled ds_read offsets; chunk ^= (row>>1)&3 within 64B rows.
// =====================================================================

struct GJobA {
  const __bf16 *Ah, *Al, *Wh, *Wl;   // A [M][K] split; W^T [N][K] split
  const float* bias;
  float* Cf; __bf16 *Ch, *Cl;
  int relu, N, blk0;
};
struct GJobsA { GJobA j[6]; };

#define BKA 32
#define NTA 64   // 2048 / 32 K-tiles

#define BARR __builtin_amdgcn_s_barrier()
#define SCHED0 __builtin_amdgcn_sched_barrier(0)
#define PRIO1 __builtin_amdgcn_s_setprio(1)
#define PRIO0 __builtin_amdgcn_s_setprio(0)

__global__ __launch_bounds__(512, 2) void gemm_phased(GJobsA P) {
  __shared__ __align__(16) __bf16 lds[2][4][256 * BKA];  // 128 KB

  const int tid = threadIdx.x;
  const int wid = tid >> 6, lane = tid & 63;
  const int lane15 = lane & 15, c0 = lane >> 4;

  // job select from flat block id
  const int bid = blockIdx.x;
  int ji = 0;
#pragma unroll
  for (int k = 1; k < 6; ++k)
    if (bid >= P.j[k].blk0) ji = k;
  const GJobA J = P.j[ji];
  const int local = bid - J.blk0;
  const int nbx = J.N >> 8;                 // 8 or 4 (power of two)
  const int bx = local & (nbx - 1);
  const int by = local / nbx;
  const int m0 = by * 256, n0 = bx * 256;

  const int wr = wid >> 2, wc = wid & 3;    // 2(M) x 4(N) waves -> 128x64 each

  // staging: per thread 2 chunks (16B) per array; source pre-swizzled
  int srow[2], soff[2];
#pragma unroll
  for (int h = 0; h < 2; ++h) {
    int s = tid + h * 512;
    int row = s >> 2;
    srow[h] = row;
    soff[h] = ((s & 3) ^ ((row >> 1) & 3)) * 8;
  }

  // fragment ds_read byte offsets (swizzled), constant across tiles
  int offB[4], offA[2][4];
#pragma unroll
  for (int ni = 0; ni < 4; ++ni) {
    int rb = wc * 64 + ni * 16 + lane15;
    offB[ni] = rb * 64 + ((c0 ^ ((rb >> 1) & 3)) << 4);
  }
#pragma unroll
  for (int mh = 0; mh < 2; ++mh)
#pragma unroll
    for (int i = 0; i < 4; ++i) {
      int ra = wr * 128 + mh * 64 + i * 16 + lane15;
      offA[mh][i] = ra * 64 + ((c0 ^ ((ra >> 1) & 3)) << 4);
    }

#define STAGE2(gptr, grow0, k1, larr)                                          \
  { _Pragma("unroll") for (int h = 0; h < 2; ++h) {                            \
      const __bf16* _src =                                                     \
          (gptr) + (size_t)((grow0) + srow[h]) * GK + (k1) + soff[h];          \
      __builtin_amdgcn_global_load_lds(                                        \
          (const __attribute__((address_space(1))) uint32_t*)_src,             \
          (__attribute__((address_space(3))) uint32_t*)((larr) +               \
              (wid * 64 + h * 512) * 8), 16, 0, 0); } }

#define DSR_A(dst, base, h)                                                    \
  { _Pragma("unroll") for (int i = 0; i < 4; ++i)                              \
      dst[i] = *(const bf16x8*)((base) + offA[h][i]); }
#define DSR_B(dst, base)                                                       \
  { _Pragma("unroll") for (int i = 0; i < 4; ++i)                              \
      dst[i] = *(const bf16x8*)((base) + offB[i]); }
#define MFMA16(af, bf, mh)                                                     \
  { _Pragma("unroll") for (int mi = 0; mi < 4; ++mi)                           \
    _Pragma("unroll") for (int ni = 0; ni < 4; ++ni)                           \
      acc[(mh) * 4 + mi][ni] = __builtin_amdgcn_mfma_f32_16x16x32_bf16(        \
          af[mi], bf[ni], acc[(mh) * 4 + mi][ni], 0, 0, 0); }

  f32x4 acc[8][4];
#pragma unroll
  for (int i = 0; i < 8; ++i)
#pragma unroll
    for (int j = 0; j < 4; ++j) acc[i][j] = (f32x4){0.f, 0.f, 0.f, 0.f};

  // prologue: stage tile 0 in FIFO order Ah,Wh,Wl,Al; gate all but Al
  STAGE2(J.Ah, m0, 0, lds[0][0]);
  STAGE2(J.Wh, n0, 0, lds[0][2]);
  STAGE2(J.Wl, n0, 0, lds[0][3]);
  STAGE2(J.Al, m0, 0, lds[0][1]);
  asm volatile("s_waitcnt vmcnt(2)" ::: "memory");   // Ah,Wh,Wl landed
  BARR;
  SCHED0;

  bf16x8 ah[4], al[4], bh[4], bl[4];

  for (int t = 0; t < NTA; ++t) {
    const int cur = t & 1, nxt = cur ^ 1;
    const bool hasNext = (t + 1 < NTA);
    const int k1 = (t + 1) * BKA;
    const char* cAh = (const char*)lds[cur][0];
    const char* cAl = (const char*)lds[cur][1];
    const char* cBh = (const char*)lds[cur][2];
    const char* cBl = (const char*)lds[cur][3];

    // ---- g0: stage Ah',Wh' | read ah0,bh,bl | MFMA ah0*bh ----
    if (hasNext) {
      STAGE2(J.Ah, m0, k1, lds[nxt][0]);
      STAGE2(J.Wh, n0, k1, lds[nxt][2]);
    }
    DSR_A(ah, cAh, 0);
    DSR_B(bh, cBh);
    DSR_B(bl, cBl);
    PRIO1; MFMA16(ah, bh, 0); PRIO0;
    if (hasNext) { asm volatile("s_waitcnt vmcnt(4)" ::: "memory"); }
    else         { asm volatile("s_waitcnt vmcnt(0)" ::: "memory"); }
    SCHED0;
    BARR;
    SCHED0;
    // ---- g1: stage Wl',Al' | read al0 | MFMA ah0*bl ----
    if (hasNext) {
      STAGE2(J.Wl, n0, k1, lds[nxt][3]);
      STAGE2(J.Al, m0, k1, lds[nxt][1]);
    }
    DSR_A(al, cAl, 0);
    PRIO1; MFMA16(ah, bl, 0); PRIO0;
    // ---- g2: read ah1 | MFMA al0*bh ----
    DSR_A(ah, cAh, 1);
    PRIO1; MFMA16(al, bh, 0); PRIO0;
    // ---- g3: read al1 | MFMA ah1*bh ----
    DSR_A(al, cAl, 1);
    PRIO1; MFMA16(ah, bh, 1); PRIO0;
    // ---- g4: MFMA ah1*bl ; MFMA al1*bh ----
    PRIO1; MFMA16(ah, bl, 1); MFMA16(al, bh, 1); PRIO0;
    if (hasNext) {
      asm volatile("s_waitcnt vmcnt(2)" ::: "memory");  // Ah',Wh',Wl' landed
      SCHED0;
      BARR;
      SCHED0;
    }
  }

  // epilogue: C/D layout col=lane&15, row=(lane>>4)*4+reg [m89]
#pragma unroll
  for (int mh = 0; mh < 2; ++mh)
#pragma unroll
    for (int mi = 0; mi < 4; ++mi)
#pragma unroll
      for (int ni = 0; ni < 4; ++ni) {
        int col = n0 + wc * 64 + ni * 16 + lane15;
        float bv = J.bias[col];
        f32x4 v = acc[mh * 4 + mi][ni];
#pragma unroll
        for (int j = 0; j < 4; ++j) {
          int row = m0 + wr * 128 + mh * 64 + mi * 16 + c0 * 4 + j;
          float x = v[j] + bv;
          if (J.relu) x = fmaxf(x, 0.0f);
          size_t o = (size_t)row * J.N + col;
          if (J.Cf) J.Cf[o] = x;
          if (J.Ch) {
            __bf16 hh = (__bf16)x;
            J.Ch[o] = hh;
            J.Cl[o] = (__bf16)(x - (float)hh);
          }
        }
      }
#undef STAGE2
#undef DSR_A
#undef DSR_B
#undef MFMA16
}

// =====================================================================
// Stage-B' combined launch: blocks [0,512) = split-K GEMM (proven
// 128x128 / BK=64 / 4-wave kernel); blocks [512,1280) = logits for the
// three stage-A-dependent routers (g/si/sg) — independent of the GEMM
// jobs, fills the launch tail.
// =====================================================================
#define BKT 64

struct GJob {
  const __bf16* Ah; const __bf16* Al;
  const __bf16* Wh; const __bf16* Wl;
  const float* bias;
  float* Cf;
  int N; int blk0; int kLen;
};
struct LJob3 { const float* Y; const float* W2; const float* b2; float* L; int K; };
struct StageBArgs { GJob gj[4]; LJob3 lj[3]; };

__global__ __launch_bounds__(256) void stageB(StageBArgs P) {
  __shared__ __align__(16) __bf16 lds[4 * 128 * BKT];
  const int bid = blockIdx.x;
  const int tid = threadIdx.x;

  if (bid >= 512) {
    // ---- logits path: lane=(expert e, k-quarter kq); 2 tokens/wave ----
    const int lid = bid - 512;
    const LJob3 J = P.lj[lid >> 8];
    const int blk = lid & 255;
    const int wid = tid >> 6, lane = tid & 63;
    const int e = lane & 15;
    const int kq = lane >> 4;
    const int tok0 = blk * 8 + wid * 2;
    const float* y0 = J.Y + (size_t)tok0 * J.K;
    const float* y1 = y0 + J.K;
    const int KQ = J.K >> 2;
    const int kbase = kq * KQ;
    float a0 = 0.f, a1 = 0.f;
#pragma unroll 8
    for (int k = 0; k < KQ; ++k) {
      int kk = kbase + k;
      float w = J.W2[(size_t)kk * EDIM + e];
      a0 = fmaf(y0[kk], w, a0);
      a1 = fmaf(y1[kk], w, a1);
    }
    a0 += __shfl_xor(a0, 16); a0 += __shfl_xor(a0, 32);
    a1 += __shfl_xor(a1, 16); a1 += __shfl_xor(a1, 32);
    if (lane < 16) {
      float b = J.b2[e];
      J.L[(size_t)tok0 * EDIM + e] = a0 + b;
      J.L[(size_t)(tok0 + 1) * EDIM + e] = a1 + b;
    }
    return;
  }

  // ---- GEMM path ----
  __bf16* ldsAh = lds;
  __bf16* ldsAl = lds + 8192;
  __bf16* ldsBh = lds + 16384;
  __bf16* ldsBl = lds + 24576;
  const char* cAh = (const char*)ldsAh;
  const char* cAl = (const char*)ldsAl;
  const char* cBh = (const char*)ldsBh;
  const char* cBl = (const char*)ldsBl;

  int ji = 0;
#pragma unroll
  for (int k = 1; k < 4; ++k)
    if (bid >= P.gj[k].blk0) ji = k;
  const GJob J = P.gj[ji];
  const int local = bid - J.blk0;
  const int nbx = J.N >> 7;
  const int bx = local & (nbx - 1);
  const int by = local / nbx;
  const int m0 = by * 128;
  const int n0 = bx * 128;

  const int wid = tid >> 6;
  const int lane = tid & 63;
  const int lane15 = lane & 15;
  const int c0 = lane >> 4;
  const int wr = wid >> 1;
  const int wc = wid & 1;

  int offA[4][2], offB[4][2];
#pragma unroll
  for (int i = 0; i < 4; ++i) {
    int ra = wr * 64 + i * 16 + lane15;
    int rb = wc * 64 + i * 16 + lane15;
#pragma unroll
    for (int ks = 0; ks < 2; ++ks) {
      offA[i][ks] = ra * 128 + (((ks * 4 + c0) ^ (ra & 7)) << 4);
      offB[i][ks] = rb * 128 + (((ks * 4 + c0) ^ (rb & 7)) << 4);
    }
  }

  f32x4 acc[4][4];
#pragma unroll
  for (int i = 0; i < 4; ++i)
#pragma unroll
    for (int j = 0; j < 4; ++j) acc[i][j] = (f32x4){0.f, 0.f, 0.f, 0.f};

  // staging helper (same as previous rounds)
  const int r_in = lane >> 3;
  const int swz_elems = ((lane & 7) ^ r_in) << 3;
#define STG(gptr, grow0, k0, lbase)                                            \
  { _Pragma("unroll") for (int i = 0; i < 4; ++i) {                            \
      int row0 = wid * 32 + i * 8;                                             \
      const __bf16* src =                                                      \
          (gptr) + (size_t)((grow0) + row0 + r_in) * GK + (k0) + swz_elems;    \
      __builtin_amdgcn_global_load_lds(                                        \
          (const __attribute__((address_space(1))) uint32_t*)src,              \
          (__attribute__((address_space(3))) uint32_t*)((lbase) + row0 * BKT), \
          16, 0, 0); } }

  for (int k0 = 0; k0 < J.kLen; k0 += BKT) {
    STG(J.Ah, m0, k0, ldsAh);
    STG(J.Al, m0, k0, ldsAl);
    STG(J.Wh, n0, k0, ldsBh);
    STG(J.Wl, n0, k0, ldsBl);
    __syncthreads();
#pragma unroll
    for (int ks = 0; ks < 2; ++ks) {
      bf16x8 ah[4], al[4], bh[4], bl[4];
#pragma unroll
      for (int i = 0; i < 4; ++i) {
        ah[i] = *(const bf16x8*)(cAh + offA[i][ks]);
        al[i] = *(const bf16x8*)(cAl + offA[i][ks]);
        bh[i] = *(const bf16x8*)(cBh + offB[i][ks]);
        bl[i] = *(const bf16x8*)(cBl + offB[i][ks]);
      }
#pragma unroll
      for (int mi = 0; mi < 4; ++mi)
#pragma unroll
        for (int ni = 0; ni < 4; ++ni) {
          acc[mi][ni] = __builtin_amdgcn_mfma_f32_16x16x32_bf16(
              ah[mi], bh[ni], acc[mi][ni], 0, 0, 0);
          acc[mi][ni] = __builtin_amdgcn_mfma_f32_16x16x32_bf16(
              ah[mi], bl[ni], acc[mi][ni], 0, 0, 0);
          acc[mi][ni] = __builtin_amdgcn_mfma_f32_16x16x32_bf16(
              al[mi], bh[ni], acc[mi][ni], 0, 0, 0);
        }
    }
    __syncthreads();
  }
#undef STG

#pragma unroll
  for (int mi = 0; mi < 4; ++mi) {
#pragma unroll
    for (int ni = 0; ni < 4; ++ni) {
      int col = n0 + wc * 64 + ni * 16 + lane15;
      float bv = J.bias[col];
      f32x4 v = acc[mi][ni];
#pragma unroll
      for (int j = 0; j < 4; ++j) {
        int row = m0 + wr * 64 + mi * 16 + c0 * 4 + j;
        float x = v[j] + bv;
        J.Cf[(size_t)row * J.N + col] = x;
      }
    }
  }
}

// =====================================================================
// prep: fused preprocessing — d_out zeroing + 4 elementwise splits +
// 6 transpose-splits + 2 prebias reductions, one dispatch via flat
// block-range job table.  Ranges:
//   [0, ZB)              : zero d_out (4096 floats/block, float4)
//   [ZB, ZB+16384)       : fp32 -> hi/lo bf16 splits
//   [ZB+16384, ZB+32768) : W -> W^T hi/lo transpose-splits
//   [ZB+32768, ZB+32832) : prebias (atomicAdd into pre-zeroed vsc/vsb)
// =====================================================================
struct SJob { const float* in; __bf16* h; __bf16* l; };
struct TJob { const float* W; __bf16* Th; __bf16* Tl; int Nd; };
struct PrepArgs {
  float* dout; int out_size; int zb;
  SJob s[4];
  TJob t[6];
  const float* pb2;
  const float* pW1a; const float* pb1a; float* pva;
  const float* pW1b; const float* pb1b; float* pvb;
};

__global__ __launch_bounds__(256) void prep(PrepArgs P) {
  __shared__ float tbuf[32][33];
  const int bid = blockIdx.x;
  const int tid = threadIdx.x;
  if (bid < P.zb) {
    // zero 4096 floats per block
    const int n4 = P.out_size >> 2;
    float4 z = {0.f, 0.f, 0.f, 0.f};
#pragma unroll
    for (int it = 0; it < 4; ++it) {
      int i = bid * 1024 + it * 256 + tid;
      if (i < n4) ((float4*)P.dout)[i] = z;
    }
    if (bid == 0 && tid < 4) {
      int i = (n4 << 2) + tid;
      if (i < P.out_size) P.dout[i] = 0.0f;
    }
    return;
  }
  const int rb = bid - P.zb;
  if (rb < 16384) {
    SJob J = P.s[rb >> 12];
    int i = (rb & 4095) * 256 + tid;
    float4 v = ((const float4*)J.in)[i];
    bf16x4 hv, lv;
    hv.x = (__bf16)v.x; lv.x = (__bf16)(v.x - (float)hv.x);
    hv.y = (__bf16)v.y; lv.y = (__bf16)(v.y - (float)hv.y);
    hv.z = (__bf16)v.z; lv.z = (__bf16)(v.z - (float)hv.z);
    hv.w = (__bf16)v.w; lv.w = (__bf16)(v.w - (float)hv.w);
    ((bf16x4*)J.h)[i] = hv;
    ((bf16x4*)J.l)[i] = lv;
  } else if (rb < 32768) {
    int local = rb - 16384;
    int ji, ln;
    if (local < 4096)      { ji = 0; ln = local; }
    else if (local < 8192) { ji = 1; ln = local - 4096; }
    else { ji = 2 + ((local - 8192) >> 11); ln = (local - 8192) & 2047; }
    TJob J = P.t[ji];
    int full = (J.Nd == HDIM);
    int n0 = (full ? (ln & 63) : (ln & 31)) * 32;
    int k0 = (full ? (ln >> 6) : (ln >> 5)) * 32;
    int tx = tid & 31, ty = tid >> 5;
#pragma unroll
    for (int i = 0; i < 4; ++i) {
      int kk = ty + i * 8;
      tbuf[kk][tx] = J.W[(size_t)(k0 + kk) * J.Nd + n0 + tx];
    }
    __syncthreads();
#pragma unroll
    for (int i = 0; i < 4; ++i) {
      int nn = ty + i * 8;
      float v = tbuf[tx][nn];
      __bf16 hh = (__bf16)v;
      size_t o = (size_t)(n0 + nn) * GK + k0 + tx;
      J.Th[o] = hh;
      J.Tl[o] = (__bf16)(v - (float)hh);
    }
  } else {
    int local = rb - 32768;                  // 64 blocks: 2 sides x 8 k x 4 n
    int side = local >> 5; int r = local & 31;
    const float* W1 = side ? P.pW1b : P.pW1a;
    const float* b1 = side ? P.pb1b : P.pb1a;
    float* v = side ? P.pvb : P.pva;
    int n = (r & 3) * 256 + tid;
    int k0 = (r >> 2) * 256;
    float acc = (k0 == 0) ? b1[n] : 0.0f;
#pragma unroll 8
    for (int k = 0; k < 256; ++k)
      acc = fmaf(P.pb2[k0 + k], W1[(size_t)(k0 + k) * HHALF + n], acc);
    atomicAdd(&v[n], acc);
  }
}

// ---------------- Skinny logits for sc/sb (sum 2 partials + relu) ----------------
struct LJob { const float* Y; const float* Y2; const float* W2;
              const float* b2; float* L; };
struct LJobs { LJob j[2]; };
__global__ __launch_bounds__(256) void logits_kernel(LJobs P) {
  const LJob J = P.j[blockIdx.x >> 8];
  const int blk = blockIdx.x & 255;
  const int tid = threadIdx.x;
  const int wid = tid >> 6, lane = tid & 63;
  const int e = lane & 15;
  const int kq = lane >> 4;
  const int tok0 = blk * 8 + wid * 2;
  const float* y0 = J.Y + (size_t)tok0 * HHALF;
  const float* y1 = y0 + HHALF;
  const float* z0 = J.Y2 + (size_t)tok0 * HHALF;
  const float* z1 = z0 + HHALF;
  const int KQ = HHALF >> 2;
  const int kbase = kq * KQ;
  float a0 = 0.f, a1 = 0.f;
#pragma unroll 8
  for (int k = 0; k < KQ; ++k) {
    int kk = kbase + k;
    float w = J.W2[(size_t)kk * EDIM + e];
    float v0 = fmaxf(y0[kk] + z0[kk], 0.0f);
    float v1 = fmaxf(y1[kk] + z1[kk], 0.0f);
    a0 = fmaf(v0, w, a0);
    a1 = fmaf(v1, w, a1);
  }
  a0 += __shfl_xor(a0, 16); a0 += __shfl_xor(a0, 32);
  a1 += __shfl_xor(a1, 16); a1 += __shfl_xor(a1, 32);
  if (lane < 16) {
    float b = J.b2[e];
    J.L[(size_t)tok0 * EDIM + e] = a0 + b;
    J.L[(size_t)(tok0 + 1) * EDIM + e] = a1 + b;
  }
}

// ---------------- Router finalize ----------------
__device__ __forceinline__ void softmax16(const float* __restrict__ L, float* __restrict__ p) {
  float v[16];
  *(float4*)&v[0]  = *(const float4*)&L[0];
  *(float4*)&v[4]  = *(const float4*)&L[4];
  *(float4*)&v[8]  = *(const float4*)&L[8];
  *(float4*)&v[12] = *(const float4*)&L[12];
  float m = v[0];
#pragma unroll
  for (int e = 1; e < 16; ++e) m = fmaxf(m, v[e]);
  float s = 0.0f;
#pragma unroll
  for (int e = 0; e < 16; ++e) { v[e] = expf(v[e] - m); s += v[e]; }
  float inv = 1.0f / s;
#pragma unroll
  for (int e = 0; e < 16; ++e) p[e] = v[e] * inv;
}

__global__ __launch_bounds__(256) void finalize_kernel(
    const float* __restrict__ Lg, const float* __restrict__ Lsi,
    const float* __restrict__ Lsg, const float* __restrict__ Lsc,
    const float* __restrict__ Lsb,
    float* __restrict__ dispatch, float* __restrict__ combine,
    float* __restrict__ router_probs, float* __restrict__ mean_acc) {
  __shared__ float sm[EDIM];
  int tid = threadIdx.x;
  if (tid < EDIM) sm[tid] = 0.0f;
  __syncthreads();

  int tok = blockIdx.x * 256 + tid;
  float pg[16], ps[16], tmp[16], r[16];
  softmax16(Lg + (size_t)tok * EDIM, pg);
  softmax16(Lsi + (size_t)tok * EDIM, ps);
  softmax16(Lsg + (size_t)tok * EDIM, tmp);
#pragma unroll
  for (int e = 0; e < 16; ++e) ps[e] += tmp[e];
  softmax16(Lsc + (size_t)tok * EDIM, tmp);
#pragma unroll
  for (int e = 0; e < 16; ++e) ps[e] += tmp[e];
  softmax16(Lsb + (size_t)tok * EDIM, tmp);
#pragma unroll
  for (int e = 0; e < 16; ++e) ps[e] += tmp[e];

#pragma unroll
  for (int e = 0; e < 16; ++e) {
    float s = ps[e] * 0.5f;
    r[e] = 0.7f * pg[e] + 0.3f * s;
  }

#pragma unroll
  for (int e = 0; e < 16; e += 4) {
    float4 o = {r[e], r[e + 1], r[e + 2], r[e + 3]};
    *(float4*)&router_probs[(size_t)tok * EDIM + e] = o;
  }

#pragma unroll
  for (int e = 0; e < 16; ++e) atomicAdd(&sm[e], r[e]);

  bool used[16];
#pragma unroll
  for (int e = 0; e < 16; ++e) used[e] = false;
  int idx[TOPK];
  float tp[TOPK];
  float tsum = 0.0f;
#pragma unroll
  for (int j = 0; j < TOPK; ++j) {
    float best = -1.0f;
    int bi = 0;
#pragma unroll
    for (int e = 0; e < 16; ++e) {
      bool take = (!used[e]) && (r[e] > best);
      best = take ? r[e] : best;
      bi = take ? e : bi;
    }
    used[bi] = true;
    idx[j] = bi;
    tp[j] = best;
    tsum += best;
  }
  float invt = 1.0f / tsum;
#pragma unroll
  for (int j = 0; j < TOPK; ++j) {
    size_t off = ((size_t)tok * EDIM + idx[j]) * CAPV;
    dispatch[off] = 1.0f;
    combine[off] = tp[j] * invt;
  }

  __syncthreads();
  if (tid < EDIM) atomicAdd(&mean_acc[tid], sm[tid]);
}

__global__ void aux_kernel(const float* __restrict__ mean_acc, float* __restrict__ out_aux) {
  if (threadIdx.x == 0 && blockIdx.x == 0) {
    float s = 0.0f;
    for (int e = 0; e < EDIM; ++e) {
      float m = mean_acc[e] * (1.0f / (float)NTOK);
      s += m * logf(m * (float)EDIM + 1e-9f);
    }
    *out_aux = s;
  }
}

// ---------------- launch ----------------
#define MBYTE (1ull << 20)

extern "C" void kernel_launch(void* const* d_in, const int* in_sizes, int n_in,
                              void* d_out, int out_size, void* d_ws, size_t ws_size,
                              hipStream_t stream) {
  const float* X    = (const float*)d_in[0];
  const float* IMG  = (const float*)d_in[1];
  const float* GEN  = (const float*)d_in[2];
  const float* g_w1 = (const float*)d_in[3];
  const float* g_b1 = (const float*)d_in[4];
  const float* g_w2 = (const float*)d_in[5];
  const float* g_b2 = (const float*)d_in[6];
  const float* m_w1 = (const float*)d_in[7];
  const float* m_b1 = (const float*)d_in[8];
  const float* m_w2 = (const float*)d_in[9];
  const float* m_b2 = (const float*)d_in[10];
  const float* si_w1 = (const float*)d_in[11];
  const float* si_b1 = (const float*)d_in[12];
  const float* si_w2 = (const float*)d_in[13];
  const float* si_b2 = (const float*)d_in[14];
  const float* sg_w1 = (const float*)d_in[15];
  const float* sg_b1 = (const float*)d_in[16];
  const float* sg_w2 = (const float*)d_in[17];
  const float* sg_b2 = (const float*)d_in[18];
  const float* sc_w1 = (const float*)d_in[19];
  const float* sc_b1 = (const float*)d_in[20];
  const float* sc_w2 = (const float*)d_in[21];
  const float* sc_b2 = (const float*)d_in[22];
  const float* sb_w1 = (const float*)d_in[23];
  const float* sb_b1 = (const float*)d_in[24];
  const float* sb_w2 = (const float*)d_in[25];
  const float* sb_b2 = (const float*)d_in[26];

  char* wsb = (char*)d_ws;
  __bf16* Xh    = (__bf16*)(wsb + 0 * MBYTE);
  __bf16* Xl    = (__bf16*)(wsb + 8 * MBYTE);
  __bf16* IMGh  = (__bf16*)(wsb + 16 * MBYTE);
  __bf16* IMGl  = (__bf16*)(wsb + 24 * MBYTE);
  __bf16* GENh  = (__bf16*)(wsb + 32 * MBYTE);
  __bf16* GENl  = (__bf16*)(wsb + 40 * MBYTE);
  __bf16* M2h   = (__bf16*)(wsb + 48 * MBYTE);   // m_w2 elementwise split
  __bf16* M2l   = (__bf16*)(wsb + 56 * MBYTE);
  __bf16* Wm1h  = (__bf16*)(wsb + 64 * MBYTE);
  __bf16* Wm1l  = (__bf16*)(wsb + 72 * MBYTE);
  __bf16* Wg1h  = (__bf16*)(wsb + 80 * MBYTE);
  __bf16* Wg1l  = (__bf16*)(wsb + 88 * MBYTE);
  __bf16* Wsch  = (__bf16*)(wsb + 96 * MBYTE);
  __bf16* Wscl  = (__bf16*)(wsb + 100 * MBYTE);
  __bf16* Wsbh  = (__bf16*)(wsb + 104 * MBYTE);
  __bf16* Wsbl  = (__bf16*)(wsb + 108 * MBYTE);
  __bf16* Wsih  = (__bf16*)(wsb + 112 * MBYTE);
  __bf16* Wsil  = (__bf16*)(wsb + 116 * MBYTE);
  __bf16* Wsgh  = (__bf16*)(wsb + 120 * MBYTE);
  __bf16* Wsgl  = (__bf16*)(wsb + 124 * MBYTE);
  __bf16* H1h   = (__bf16*)(wsb + 128 * MBYTE);
  __bf16* H1l   = (__bf16*)(wsb + 136 * MBYTE);
  __bf16* WPsch = (__bf16*)(wsb + 144 * MBYTE);  // (m_w2@sc_w1)^T split [1024][2048]
  __bf16* WPscl = (__bf16*)(wsb + 148 * MBYTE);
  __bf16* WPsbh = (__bf16*)(wsb + 152 * MBYTE);
  __bf16* WPsbl = (__bf16*)(wsb + 156 * MBYTE);
  float*  YG    = (float*)(wsb + 160 * MBYTE);
  float*  YSI   = (float*)(wsb + 176 * MBYTE);
  float*  YSG   = (float*)(wsb + 184 * MBYTE);
  float*  YSCp0 = (float*)(wsb + 192 * MBYTE);   // split-K partials (bias in p0)
  float*  YSCp1 = (float*)(wsb + 200 * MBYTE);
  float*  YSBp0 = (float*)(wsb + 208 * MBYTE);
  float*  YSBp1 = (float*)(wsb + 216 * MBYTE);
  float* L0 = (float*)(wsb + 224 * MBYTE);
  float* L1 = L0 + NTOK * EDIM;
  float* L2 = L1 + NTOK * EDIM;
  float* L3 = L2 + NTOK * EDIM;
  float* L4 = L3 + NTOK * EDIM;
  float* meanp = L4 + NTOK * EDIM;
  float* zbias = meanp + EDIM;         // 2048 zeros (bias for W'/kh1 jobs)
  float* vsc = zbias + GK;
  float* vsb = vsc + HHALF;

  float* dispatch = (float*)d_out;
  float* combine = dispatch + (size_t)NTOK * EDIM * CAPV;
  float* rp = combine + (size_t)NTOK * EDIM * CAPV;
  float* aux = rp + (size_t)NTOK * EDIM;

  // small zero (atomicAdd targets + zbias) — must precede prep
  hipMemsetAsync(meanp, 0, (EDIM + GK + 2 * HHALF) * sizeof(float), stream);

  dim3 blk(256);
  const int zb = (out_size + 4095) / 4096;   // blocks zeroing d_out

  // 1) fused prep: d_out zero + splits + transpose-splits + prebias
  {
    PrepArgs p;
    p.dout = (float*)d_out; p.out_size = out_size; p.zb = zb;
    p.s[0] = {X, Xh, Xl};
    p.s[1] = {IMG, IMGh, IMGl};
    p.s[2] = {GEN, GENh, GENl};
    p.s[3] = {m_w2, M2h, M2l};
    p.t[0] = {m_w1, Wm1h, Wm1l, HDIM};
    p.t[1] = {g_w1, Wg1h, Wg1l, HDIM};
    p.t[2] = {sc_w1, Wsch, Wscl, HHALF};
    p.t[3] = {sb_w1, Wsbh, Wsbl, HHALF};
    p.t[4] = {si_w1, Wsih, Wsil, HHALF};
    p.t[5] = {sg_w1, Wsgh, Wsgl, HHALF};
    p.pb2 = m_b2;
    p.pW1a = sc_w1; p.pb1a = sc_b1; p.pva = vsc;
    p.pW1b = sb_w1; p.pb1b = sb_b1; p.pvb = vsb;
    prep<<<zb + 32832, blk, 0, stream>>>(p);
  }

  // 2) GEMM stage A: 6 independent jobs, exactly 256 blocks (round-10 kernel)
  {
    GJobsA g;
    g.j[0] = {Xh, Xl, Wm1h, Wm1l, m_b1, nullptr, H1h, H1l, 1, HDIM, 0};      // 64
    g.j[1] = {Xh, Xl, Wg1h, Wg1l, g_b1, YG, nullptr, nullptr, 1, HDIM, 64};  // 64
    g.j[2] = {IMGh, IMGl, Wsih, Wsil, si_b1, YSI, nullptr, nullptr, 1, HHALF, 128}; // 32
    g.j[3] = {GENh, GENl, Wsgh, Wsgl, sg_b1, YSG, nullptr, nullptr, 1, HHALF, 160}; // 32
    g.j[4] = {Wsch, Wscl, M2h, M2l, zbias, nullptr, WPsch, WPscl, 0, HDIM, 192};    // 32 (M=1024)
    g.j[5] = {Wsbh, Wsbl, M2h, M2l, zbias, nullptr, WPsbh, WPsbl, 0, HDIM, 224};    // 32 (M=1024)
    gemm_phased<<<256, dim3(512), 0, stream>>>(g);
  }

  // 3) combined stage B' (split-K GEMM partials) + logits L0/L1/L2
  {
    StageBArgs s;
    s.gj[0] = {H1h, H1l, WPsch, WPscl, vsc, YSCp0, HHALF, 0, 1024};
    s.gj[1] = {H1h + 1024, H1l + 1024, WPsch + 1024, WPscl + 1024, zbias, YSCp1,
               HHALF, 128, 1024};
    s.gj[2] = {H1h, H1l, WPsbh, WPsbl, vsb, YSBp0, HHALF, 256, 1024};
    s.gj[3] = {H1h + 1024, H1l + 1024, WPsbh + 1024, WPsbl + 1024, zbias, YSBp1,
               HHALF, 384, 1024};
    s.lj[0] = {YG, g_w2, g_b2, L0, HDIM};
    s.lj[1] = {YSI, si_w2, si_b2, L1, HHALF};
    s.lj[2] = {YSG, sg_w2, sg_b2, L2, HHALF};
    stageB<<<512 + 768, blk, 0, stream>>>(s);
  }

  // 4) logits for sc/sb (sum partials + relu)
  {
    LJobs l;
    l.j[0] = {YSCp0, YSCp1, sc_w2, sc_b2, L3};
    l.j[1] = {YSBp0, YSBp1, sb_w2, sb_b2, L4};
    logits_kernel<<<2 * 256, blk, 0, stream>>>(l);
  }

  // 5) finalize + aux
  finalize_kernel<<<NTOK / 256, blk, 0, stream>>>(L0, L1, L2, L3, L4,
                                                  dispatch, combine, rp, meanp);
  aux_kernel<<<1, 64, 0, stream>>>(meanp, aux);
}

// Round 14
// 393.533 us; speedup vs baseline: 1.0622x; 1.0293x over previous
//
#include <hip/hip_runtime.h>
#include <math.h>
#include <stdint.h>

// Problem constants (B=2, S=1024, H=2048, E=16, K=4, CAP=768)
#define NTOK 2048
#define HDIM 2048
#define HHALF 1024
#define EDIM 16
#define CAPV 768
#define TOPK 4
#define GK 2048        // K is 2048 for every GEMM in this problem

typedef __bf16 bf16x8 __attribute__((ext_vector_type(8)));
typedef __bf16 bf16x4 __attribute__((ext_vector_type(4)));
typedef float f32x4 __attribute__((ext_vector_type(4)));

// =====================================================================
// Stage-A GEMM: round-10 read-ahead 2-barrier schedule (measured
// equilibrium: 171us / MfmaUtil 53% / 0 bank conflicts), plus T1
// XCD-aware block swizzle (grid=256, %8==0 -> wg=(bid&7)*32+(bid>>3)):
// each XCD's 32 consecutive work items share A/B panels -> L2 hits
// instead of HBM re-fetch; helps the vmcnt gates clear in-lookahead.
// Tile 256x256, BK=32, 512 thr = 8 waves (2M x 4N), per-wave 128x64.
// LDS: 2 bufs x 4 arrays (Ah,Al,Bh,Bl) x [256][32]bf16 = 128 KB.
// Per-wave vmcnt FIFO (2 loads per STAGE2), steady state:
//   g0: stage Ah',Wh' | read ah0,bh,bl | MFMA ah0*bh
//       gate vmcnt(4) -> Al(t) landed | BARRIER
//   g1: stage Wl',Al' | read al0 | MFMA ah0*bl
//   g2: read ah1 | MFMA al0*bh
//   g3: read al1 | MFMA ah1*bh
//   g4: MFMA ah1*bl ; MFMA al1*bh
//       gate vmcnt(2) -> Ah',Wh',Wl' landed | BARRIER   [exit: Al'x2]
// Swizzle rule #21: linear LDS dest + inverse-swizzled global source +
// swizzled ds_read offsets; chunk ^= (row>>1)&3 within 64B rows.
// =====================================================================

struct GJobA {
  const __bf16 *Ah, *Al, *Wh, *Wl;   // A [M][K] split; W^T [N][K] split
  const float* bias;
  float* Cf; __bf16 *Ch, *Cl;
  int relu, N, blk0;
};
struct GJobsA { GJobA j[6]; };

#define BKA 32
#define NTA 64   // 2048 / 32 K-tiles

#define BARR __builtin_amdgcn_s_barrier()
#define SCHED0 __builtin_amdgcn_sched_barrier(0)
#define PRIO1 __builtin_amdgcn_s_setprio(1)
#define PRIO0 __builtin_amdgcn_s_setprio(0)

__global__ __launch_bounds__(512, 2) void gemm_phased(GJobsA P) {
  __shared__ __align__(16) __bf16 lds[2][4][256 * BKA];  // 128 KB

  const int tid = threadIdx.x;
  const int wid = tid >> 6, lane = tid & 63;
  const int lane15 = lane & 15, c0 = lane >> 4;

  // T1 XCD swizzle (grid=256, 8 XCDs): XCD r gets work items [32r,32r+32)
  const int bid = (blockIdx.x & 7) * 32 + (blockIdx.x >> 3);
  int ji = 0;
#pragma unroll
  for (int k = 1; k < 6; ++k)
    if (bid >= P.j[k].blk0) ji = k;
  const GJobA J = P.j[ji];
  const int local = bid - J.blk0;
  const int nbx = J.N >> 8;                 // 8 or 4 (power of two)
  const int bx = local & (nbx - 1);
  const int by = local / nbx;
  const int m0 = by * 256, n0 = bx * 256;

  const int wr = wid >> 2, wc = wid & 3;    // 2(M) x 4(N) waves -> 128x64 each

  // staging: per thread 2 chunks (16B) per array; source pre-swizzled
  int srow[2], soff[2];
#pragma unroll
  for (int h = 0; h < 2; ++h) {
    int s = tid + h * 512;
    int row = s >> 2;
    srow[h] = row;
    soff[h] = ((s & 3) ^ ((row >> 1) & 3)) * 8;
  }

  // fragment ds_read byte offsets (swizzled), constant across tiles
  int offB[4], offA[2][4];
#pragma unroll
  for (int ni = 0; ni < 4; ++ni) {
    int rb = wc * 64 + ni * 16 + lane15;
    offB[ni] = rb * 64 + ((c0 ^ ((rb >> 1) & 3)) << 4);
  }
#pragma unroll
  for (int mh = 0; mh < 2; ++mh)
#pragma unroll
    for (int i = 0; i < 4; ++i) {
      int ra = wr * 128 + mh * 64 + i * 16 + lane15;
      offA[mh][i] = ra * 64 + ((c0 ^ ((ra >> 1) & 3)) << 4);
    }

#define STAGE2(gptr, grow0, k1, larr)                                          \
  { _Pragma("unroll") for (int h = 0; h < 2; ++h) {                            \
      const __bf16* _src =                                                     \
          (gptr) + (size_t)((grow0) + srow[h]) * GK + (k1) + soff[h];          \
      __builtin_amdgcn_global_load_lds(                                        \
          (const __attribute__((address_space(1))) uint32_t*)_src,             \
          (__attribute__((address_space(3))) uint32_t*)((larr) +               \
              (wid * 64 + h * 512) * 8), 16, 0, 0); } }

#define DSR_A(dst, base, h)                                                    \
  { _Pragma("unroll") for (int i = 0; i < 4; ++i)                              \
      dst[i] = *(const bf16x8*)((base) + offA[h][i]); }
#define DSR_B(dst, base)                                                       \
  { _Pragma("unroll") for (int i = 0; i < 4; ++i)                              \
      dst[i] = *(const bf16x8*)((base) + offB[i]); }
#define MFMA16(af, bf, mh)                                                     \
  { _Pragma("unroll") for (int mi = 0; mi < 4; ++mi)                           \
    _Pragma("unroll") for (int ni = 0; ni < 4; ++ni)                           \
      acc[(mh) * 4 + mi][ni] = __builtin_amdgcn_mfma_f32_16x16x32_bf16(        \
          af[mi], bf[ni], acc[(mh) * 4 + mi][ni], 0, 0, 0); }

  f32x4 acc[8][4];
#pragma unroll
  for (int i = 0; i < 8; ++i)
#pragma unroll
    for (int j = 0; j < 4; ++j) acc[i][j] = (f32x4){0.f, 0.f, 0.f, 0.f};

  // prologue: stage tile 0 in FIFO order Ah,Wh,Wl,Al; gate all but Al
  STAGE2(J.Ah, m0, 0, lds[0][0]);
  STAGE2(J.Wh, n0, 0, lds[0][2]);
  STAGE2(J.Wl, n0, 0, lds[0][3]);
  STAGE2(J.Al, m0, 0, lds[0][1]);
  asm volatile("s_waitcnt vmcnt(2)" ::: "memory");   // Ah,Wh,Wl landed
  BARR;
  SCHED0;

  bf16x8 ah[4], al[4], bh[4], bl[4];

  for (int t = 0; t < NTA; ++t) {
    const int cur = t & 1, nxt = cur ^ 1;
    const bool hasNext = (t + 1 < NTA);
    const int k1 = (t + 1) * BKA;
    const char* cAh = (const char*)lds[cur][0];
    const char* cAl = (const char*)lds[cur][1];
    const char* cBh = (const char*)lds[cur][2];
    const char* cBl = (const char*)lds[cur][3];

    // ---- g0: stage Ah',Wh' | read ah0,bh,bl | MFMA ah0*bh ----
    if (hasNext) {
      STAGE2(J.Ah, m0, k1, lds[nxt][0]);
      STAGE2(J.Wh, n0, k1, lds[nxt][2]);
    }
    DSR_A(ah, cAh, 0);
    DSR_B(bh, cBh);
    DSR_B(bl, cBl);
    PRIO1; MFMA16(ah, bh, 0); PRIO0;
    if (hasNext) { asm volatile("s_waitcnt vmcnt(4)" ::: "memory"); }
    else         { asm volatile("s_waitcnt vmcnt(0)" ::: "memory"); }
    SCHED0;
    BARR;
    SCHED0;
    // ---- g1: stage Wl',Al' | read al0 | MFMA ah0*bl ----
    if (hasNext) {
      STAGE2(J.Wl, n0, k1, lds[nxt][3]);
      STAGE2(J.Al, m0, k1, lds[nxt][1]);
    }
    DSR_A(al, cAl, 0);
    PRIO1; MFMA16(ah, bl, 0); PRIO0;
    // ---- g2: read ah1 | MFMA al0*bh ----
    DSR_A(ah, cAh, 1);
    PRIO1; MFMA16(al, bh, 0); PRIO0;
    // ---- g3: read al1 | MFMA ah1*bh ----
    DSR_A(al, cAl, 1);
    PRIO1; MFMA16(ah, bh, 1); PRIO0;
    // ---- g4: MFMA ah1*bl ; MFMA al1*bh ----
    PRIO1; MFMA16(ah, bl, 1); MFMA16(al, bh, 1); PRIO0;
    if (hasNext) {
      asm volatile("s_waitcnt vmcnt(2)" ::: "memory");  // Ah',Wh',Wl' landed
      SCHED0;
      BARR;
      SCHED0;
    }
  }

  // epilogue: C/D layout col=lane&15, row=(lane>>4)*4+reg [m89]
#pragma unroll
  for (int mh = 0; mh < 2; ++mh)
#pragma unroll
    for (int mi = 0; mi < 4; ++mi)
#pragma unroll
      for (int ni = 0; ni < 4; ++ni) {
        int col = n0 + wc * 64 + ni * 16 + lane15;
        float bv = J.bias[col];
        f32x4 v = acc[mh * 4 + mi][ni];
#pragma unroll
        for (int j = 0; j < 4; ++j) {
          int row = m0 + wr * 128 + mh * 64 + mi * 16 + c0 * 4 + j;
          float x = v[j] + bv;
          if (J.relu) x = fmaxf(x, 0.0f);
          size_t o = (size_t)row * J.N + col;
          if (J.Cf) J.Cf[o] = x;
          if (J.Ch) {
            __bf16 hh = (__bf16)x;
            J.Ch[o] = hh;
            J.Cl[o] = (__bf16)(x - (float)hh);
          }
        }
      }
#undef STAGE2
#undef DSR_A
#undef DSR_B
#undef MFMA16
}

// =====================================================================
// Stage-B' GEMM: proven 128x128 / BK=64 / 4-wave kernel, + kLen for
// split-K (pointers pre-offset by the host; partials, relu deferred).
// T1 XCD swizzle for grid=512: wg=(bid&7)*64+(bid>>3).
// =====================================================================
#define BKT 64

struct GJob {
  const __bf16* Ah; const __bf16* Al;
  const __bf16* Wh; const __bf16* Wl;
  const float* bias;
  float* Cf;
  __bf16* Ch; __bf16* Cl;
  int relu; int N; int blk0; int kLen;
};
struct GJobs { GJob j[4]; int njobs; };

__device__ __forceinline__ void stage_tile(const __bf16* __restrict__ g,
                                           int grow0, int k0,
                                           __bf16* lbase, int wid, int lane) {
  int r_in = lane >> 3;
  int swz_elems = ((lane & 7) ^ r_in) << 3;
#pragma unroll
  for (int i = 0; i < 4; ++i) {
    int row0 = wid * 32 + i * 8;
    const __bf16* src = g + (size_t)(grow0 + row0 + r_in) * GK + k0 + swz_elems;
    __builtin_amdgcn_global_load_lds(
        (const __attribute__((address_space(1))) uint32_t*)src,
        (__attribute__((address_space(3))) uint32_t*)(lbase + row0 * BKT),
        16, 0, 0);
  }
}

__global__ __launch_bounds__(256) void gemm_split(GJobs P) {
  __shared__ __align__(16) __bf16 lds[4 * 128 * BKT];
  __bf16* ldsAh = lds;
  __bf16* ldsAl = lds + 8192;
  __bf16* ldsBh = lds + 16384;
  __bf16* ldsBl = lds + 24576;
  const char* cAh = (const char*)ldsAh;
  const char* cAl = (const char*)ldsAl;
  const char* cBh = (const char*)ldsBh;
  const char* cBl = (const char*)ldsBl;

  // T1 XCD swizzle (grid=512): XCD r gets work items [64r, 64r+64)
  const int bid = (blockIdx.x & 7) * 64 + (blockIdx.x >> 3);
  int ji = 0;
#pragma unroll
  for (int k = 1; k < 4; ++k)
    if (k < P.njobs && bid >= P.j[k].blk0) ji = k;
  const GJob J = P.j[ji];
  const int local = bid - J.blk0;
  const int nbx = J.N >> 7;
  const int bx = local & (nbx - 1);
  const int by = local / nbx;
  const int m0 = by * 128;
  const int n0 = bx * 128;

  const int tid = threadIdx.x;
  const int wid = tid >> 6;
  const int lane = tid & 63;
  const int lane15 = lane & 15;
  const int c0 = lane >> 4;
  const int wr = wid >> 1;
  const int wc = wid & 1;

  int offA[4][2], offB[4][2];
#pragma unroll
  for (int i = 0; i < 4; ++i) {
    int ra = wr * 64 + i * 16 + lane15;
    int rb = wc * 64 + i * 16 + lane15;
#pragma unroll
    for (int ks = 0; ks < 2; ++ks) {
      offA[i][ks] = ra * 128 + (((ks * 4 + c0) ^ (ra & 7)) << 4);
      offB[i][ks] = rb * 128 + (((ks * 4 + c0) ^ (rb & 7)) << 4);
    }
  }

  f32x4 acc[4][4];
#pragma unroll
  for (int i = 0; i < 4; ++i)
#pragma unroll
    for (int j = 0; j < 4; ++j) acc[i][j] = (f32x4){0.f, 0.f, 0.f, 0.f};

  for (int k0 = 0; k0 < J.kLen; k0 += BKT) {
    stage_tile(J.Ah, m0, k0, ldsAh, wid, lane);
    stage_tile(J.Al, m0, k0, ldsAl, wid, lane);
    stage_tile(J.Wh, n0, k0, ldsBh, wid, lane);
    stage_tile(J.Wl, n0, k0, ldsBl, wid, lane);
    __syncthreads();
#pragma unroll
    for (int ks = 0; ks < 2; ++ks) {
      bf16x8 ah[4], al[4], bh[4], bl[4];
#pragma unroll
      for (int i = 0; i < 4; ++i) {
        ah[i] = *(const bf16x8*)(cAh + offA[i][ks]);
        al[i] = *(const bf16x8*)(cAl + offA[i][ks]);
        bh[i] = *(const bf16x8*)(cBh + offB[i][ks]);
        bl[i] = *(const bf16x8*)(cBl + offB[i][ks]);
      }
#pragma unroll
      for (int mi = 0; mi < 4; ++mi)
#pragma unroll
        for (int ni = 0; ni < 4; ++ni) {
          acc[mi][ni] = __builtin_amdgcn_mfma_f32_16x16x32_bf16(
              ah[mi], bh[ni], acc[mi][ni], 0, 0, 0);
          acc[mi][ni] = __builtin_amdgcn_mfma_f32_16x16x32_bf16(
              ah[mi], bl[ni], acc[mi][ni], 0, 0, 0);
          acc[mi][ni] = __builtin_amdgcn_mfma_f32_16x16x32_bf16(
              al[mi], bh[ni], acc[mi][ni], 0, 0, 0);
        }
    }
    __syncthreads();
  }

#pragma unroll
  for (int mi = 0; mi < 4; ++mi) {
#pragma unroll
    for (int ni = 0; ni < 4; ++ni) {
      int col = n0 + wc * 64 + ni * 16 + lane15;
      float bv = J.bias[col];
      f32x4 v = acc[mi][ni];
#pragma unroll
      for (int j = 0; j < 4; ++j) {
        int row = m0 + wr * 64 + mi * 16 + c0 * 4 + j;
        float x = v[j] + bv;
        if (J.relu) x = fmaxf(x, 0.0f);
        size_t o = (size_t)row * J.N + col;
        if (J.Cf) J.Cf[o] = x;
        if (J.Ch) {
          __bf16 hh = (__bf16)x;
          J.Ch[o] = hh;
          J.Cl[o] = (__bf16)(x - (float)hh);
        }
      }
    }
  }
}

// =====================================================================
// prep: fused preprocessing — 4 elementwise splits + 6 transpose-splits
// + 2 prebias reductions, one dispatch via flat block-range job table.
// (d_out zeroing stays in hipMemsetAsync — fill engine is faster and
// doesn't delay the split outputs stage A waits on; round-13 lesson.)
// =====================================================================
struct SJob { const float* in; __bf16* h; __bf16* l; };
struct TJob { const float* W; __bf16* Th; __bf16* Tl; int Nd; };
struct PrepArgs {
  SJob s[4];
  TJob t[6];
  const float* pb2;
  const float* pW1a; const float* pb1a; float* pva;
  const float* pW1b; const float* pb1b; float* pvb;
};

__global__ __launch_bounds__(256) void prep(PrepArgs P) {
  __shared__ float tbuf[32][33];
  const int bid = blockIdx.x;
  const int tid = threadIdx.x;
  if (bid < 16384) {
    SJob J = P.s[bid >> 12];
    int i = (bid & 4095) * 256 + tid;
    float4 v = ((const float4*)J.in)[i];
    bf16x4 hv, lv;
    hv.x = (__bf16)v.x; lv.x = (__bf16)(v.x - (float)hv.x);
    hv.y = (__bf16)v.y; lv.y = (__bf16)(v.y - (float)hv.y);
    hv.z = (__bf16)v.z; lv.z = (__bf16)(v.z - (float)hv.z);
    hv.w = (__bf16)v.w; lv.w = (__bf16)(v.w - (float)hv.w);
    ((bf16x4*)J.h)[i] = hv;
    ((bf16x4*)J.l)[i] = lv;
  } else if (bid < 32768) {
    int local = bid - 16384;
    int ji, ln;
    if (local < 4096)      { ji = 0; ln = local; }
    else if (local < 8192) { ji = 1; ln = local - 4096; }
    else { ji = 2 + ((local - 8192) >> 11); ln = (local - 8192) & 2047; }
    TJob J = P.t[ji];
    int full = (J.Nd == HDIM);
    int n0 = (full ? (ln & 63) : (ln & 31)) * 32;
    int k0 = (full ? (ln >> 6) : (ln >> 5)) * 32;
    int tx = tid & 31, ty = tid >> 5;
#pragma unroll
    for (int i = 0; i < 4; ++i) {
      int kk = ty + i * 8;
      tbuf[kk][tx] = J.W[(size_t)(k0 + kk) * J.Nd + n0 + tx];
    }
    __syncthreads();
#pragma unroll
    for (int i = 0; i < 4; ++i) {
      int nn = ty + i * 8;
      float v = tbuf[tx][nn];
      __bf16 hh = (__bf16)v;
      size_t o = (size_t)(n0 + nn) * GK + k0 + tx;
      J.Th[o] = hh;
      J.Tl[o] = (__bf16)(v - (float)hh);
    }
  } else {
    int local = bid - 32768;                 // 64 blocks: 2 sides x 8 k x 4 n
    int side = local >> 5; int r = local & 31;
    const float* W1 = side ? P.pW1b : P.pW1a;
    const float* b1 = side ? P.pb1b : P.pb1a;
    float* v = side ? P.pvb : P.pva;
    int n = (r & 3) * 256 + tid;
    int k0 = (r >> 2) * 256;
    float acc = (k0 == 0) ? b1[n] : 0.0f;
#pragma unroll 8
    for (int k = 0; k < 256; ++k)
      acc = fmaf(P.pb2[k0 + k], W1[(size_t)(k0 + k) * HHALF + n], acc);
    atomicAdd(&v[n], acc);
  }
}

// ---------------- Skinny logits, 5 routers batched ----------------
struct LJob { const float* Y; const float* Y2; const float* W2;
              const float* b2; float* L; int K; int relu; };
struct LJobs { LJob j[5]; };
__global__ __launch_bounds__(256) void logits_kernel(LJobs P) {
  const LJob J = P.j[blockIdx.x >> 8];
  const int blk = blockIdx.x & 255;
  const int tid = threadIdx.x;
  const int wid = tid >> 6, lane = tid & 63;
  const int e = lane & 15;
  const int kq = lane >> 4;
  const int tok0 = blk * 8 + wid * 2;
  const float* y0 = J.Y + (size_t)tok0 * J.K;
  const float* y1 = y0 + J.K;
  const float* z0 = J.Y2 + (size_t)tok0 * J.K;
  const float* z1 = z0 + J.K;
  const int KQ = J.K >> 2;
  const int kbase = kq * KQ;
  float a0 = 0.f, a1 = 0.f;
  if (J.relu) {
#pragma unroll 8
    for (int k = 0; k < KQ; ++k) {
      int kk = kbase + k;
      float w = J.W2[(size_t)kk * EDIM + e];
      float v0 = fmaxf(y0[kk] + z0[kk], 0.0f);
      float v1 = fmaxf(y1[kk] + z1[kk], 0.0f);
      a0 = fmaf(v0, w, a0);
      a1 = fmaf(v1, w, a1);
    }
  } else {
#pragma unroll 8
    for (int k = 0; k < KQ; ++k) {
      int kk = kbase + k;
      float w = J.W2[(size_t)kk * EDIM + e];
      a0 = fmaf(y0[kk], w, a0);
      a1 = fmaf(y1[kk], w, a1);
    }
  }
  a0 += __shfl_xor(a0, 16); a0 += __shfl_xor(a0, 32);
  a1 += __shfl_xor(a1, 16); a1 += __shfl_xor(a1, 32);
  if (lane < 16) {
    float b = J.b2[e];
    J.L[(size_t)tok0 * EDIM + e] = a0 + b;
    J.L[(size_t)(tok0 + 1) * EDIM + e] = a1 + b;
  }
}

// ---------------- Router finalize ----------------
__device__ __forceinline__ void softmax16(const float* __restrict__ L, float* __restrict__ p) {
  float v[16];
  *(float4*)&v[0]  = *(const float4*)&L[0];
  *(float4*)&v[4]  = *(const float4*)&L[4];
  *(float4*)&v[8]  = *(const float4*)&L[8];
  *(float4*)&v[12] = *(const float4*)&L[12];
  float m = v[0];
#pragma unroll
  for (int e = 1; e < 16; ++e) m = fmaxf(m, v[e]);
  float s = 0.0f;
#pragma unroll
  for (int e = 0; e < 16; ++e) { v[e] = expf(v[e] - m); s += v[e]; }
  float inv = 1.0f / s;
#pragma unroll
  for (int e = 0; e < 16; ++e) p[e] = v[e] * inv;
}

__global__ __launch_bounds__(256) void finalize_kernel(
    const float* __restrict__ Lg, const float* __restrict__ Lsi,
    const float* __restrict__ Lsg, const float* __restrict__ Lsc,
    const float* __restrict__ Lsb,
    float* __restrict__ dispatch, float* __restrict__ combine,
    float* __restrict__ router_probs, float* __restrict__ mean_acc) {
  __shared__ float sm[EDIM];
  int tid = threadIdx.x;
  if (tid < EDIM) sm[tid] = 0.0f;
  __syncthreads();

  int tok = blockIdx.x * 256 + tid;
  float pg[16], ps[16], tmp[16], r[16];
  softmax16(Lg + (size_t)tok * EDIM, pg);
  softmax16(Lsi + (size_t)tok * EDIM, ps);
  softmax16(Lsg + (size_t)tok * EDIM, tmp);
#pragma unroll
  for (int e = 0; e < 16; ++e) ps[e] += tmp[e];
  softmax16(Lsc + (size_t)tok * EDIM, tmp);
#pragma unroll
  for (int e = 0; e < 16; ++e) ps[e] += tmp[e];
  softmax16(Lsb + (size_t)tok * EDIM, tmp);
#pragma unroll
  for (int e = 0; e < 16; ++e) ps[e] += tmp[e];

#pragma unroll
  for (int e = 0; e < 16; ++e) {
    float s = ps[e] * 0.5f;
    r[e] = 0.7f * pg[e] + 0.3f * s;
  }

#pragma unroll
  for (int e = 0; e < 16; e += 4) {
    float4 o = {r[e], r[e + 1], r[e + 2], r[e + 3]};
    *(float4*)&router_probs[(size_t)tok * EDIM + e] = o;
  }

#pragma unroll
  for (int e = 0; e < 16; ++e) atomicAdd(&sm[e], r[e]);

  bool used[16];
#pragma unroll
  for (int e = 0; e < 16; ++e) used[e] = false;
  int idx[TOPK];
  float tp[TOPK];
  float tsum = 0.0f;
#pragma unroll
  for (int j = 0; j < TOPK; ++j) {
    float best = -1.0f;
    int bi = 0;
#pragma unroll
    for (int e = 0; e < 16; ++e) {
      bool take = (!used[e]) && (r[e] > best);
      best = take ? r[e] : best;
      bi = take ? e : bi;
    }
    used[bi] = true;
    idx[j] = bi;
    tp[j] = best;
    tsum += best;
  }
  float invt = 1.0f / tsum;
#pragma unroll
  for (int j = 0; j < TOPK; ++j) {
    size_t off = ((size_t)tok * EDIM + idx[j]) * CAPV;
    dispatch[off] = 1.0f;
    combine[off] = tp[j] * invt;
  }

  __syncthreads();
  if (tid < EDIM) atomicAdd(&mean_acc[tid], sm[tid]);
}

__global__ void aux_kernel(const float* __restrict__ mean_acc, float* __restrict__ out_aux) {
  if (threadIdx.x == 0 && blockIdx.x == 0) {
    float s = 0.0f;
    for (int e = 0; e < EDIM; ++e) {
      float m = mean_acc[e] * (1.0f / (float)NTOK);
      s += m * logf(m * (float)EDIM + 1e-9f);
    }
    *out_aux = s;
  }
}

// ---------------- launch ----------------
#define MBYTE (1ull << 20)

extern "C" void kernel_launch(void* const* d_in, const int* in_sizes, int n_in,
                              void* d_out, int out_size, void* d_ws, size_t ws_size,
                              hipStream_t stream) {
  const float* X    = (const float*)d_in[0];
  const float* IMG  = (const float*)d_in[1];
  const float* GEN  = (const float*)d_in[2];
  const float* g_w1 = (const float*)d_in[3];
  const float* g_b1 = (const float*)d_in[4];
  const float* g_w2 = (const float*)d_in[5];
  const float* g_b2 = (const float*)d_in[6];
  const float* m_w1 = (const float*)d_in[7];
  const float* m_b1 = (const float*)d_in[8];
  const float* m_w2 = (const float*)d_in[9];
  const float* m_b2 = (const float*)d_in[10];
  const float* si_w1 = (const float*)d_in[11];
  const float* si_b1 = (const float*)d_in[12];
  const float* si_w2 = (const float*)d_in[13];
  const float* si_b2 = (const float*)d_in[14];
  const float* sg_w1 = (const float*)d_in[15];
  const float* sg_b1 = (const float*)d_in[16];
  const float* sg_w2 = (const float*)d_in[17];
  const float* sg_b2 = (const float*)d_in[18];
  const float* sc_w1 = (const float*)d_in[19];
  const float* sc_b1 = (const float*)d_in[20];
  const float* sc_w2 = (const float*)d_in[21];
  const float* sc_b2 = (const float*)d_in[22];
  const float* sb_w1 = (const float*)d_in[23];
  const float* sb_b1 = (const float*)d_in[24];
  const float* sb_w2 = (const float*)d_in[25];
  const float* sb_b2 = (const float*)d_in[26];

  char* wsb = (char*)d_ws;
  __bf16* Xh    = (__bf16*)(wsb + 0 * MBYTE);
  __bf16* Xl    = (__bf16*)(wsb + 8 * MBYTE);
  __bf16* IMGh  = (__bf16*)(wsb + 16 * MBYTE);
  __bf16* IMGl  = (__bf16*)(wsb + 24 * MBYTE);
  __bf16* GENh  = (__bf16*)(wsb + 32 * MBYTE);
  __bf16* GENl  = (__bf16*)(wsb + 40 * MBYTE);
  __bf16* M2h   = (__bf16*)(wsb + 48 * MBYTE);   // m_w2 elementwise split
  __bf16* M2l   = (__bf16*)(wsb + 56 * MBYTE);
  __bf16* Wm1h  = (__bf16*)(wsb + 64 * MBYTE);
  __bf16* Wm1l  = (__bf16*)(wsb + 72 * MBYTE);
  __bf16* Wg1h  = (__bf16*)(wsb + 80 * MBYTE);
  __bf16* Wg1l  = (__bf16*)(wsb + 88 * MBYTE);
  __bf16* Wsch  = (__bf16*)(wsb + 96 * MBYTE);
  __bf16* Wscl  = (__bf16*)(wsb + 100 * MBYTE);
  __bf16* Wsbh  = (__bf16*)(wsb + 104 * MBYTE);
  __bf16* Wsbl  = (__bf16*)(wsb + 108 * MBYTE);
  __bf16* Wsih  = (__bf16*)(wsb + 112 * MBYTE);
  __bf16* Wsil  = (__bf16*)(wsb + 116 * MBYTE);
  __bf16* Wsgh  = (__bf16*)(wsb + 120 * MBYTE);
  __bf16* Wsgl  = (__bf16*)(wsb + 124 * MBYTE);
  __bf16* H1h   = (__bf16*)(wsb + 128 * MBYTE);
  __bf16* H1l   = (__bf16*)(wsb + 136 * MBYTE);
  __bf16* WPsch = (__bf16*)(wsb + 144 * MBYTE);  // (m_w2@sc_w1)^T split [1024][2048]
  __bf16* WPscl = (__bf16*)(wsb + 148 * MBYTE);
  __bf16* WPsbh = (__bf16*)(wsb + 152 * MBYTE);
  __bf16* WPsbl = (__bf16*)(wsb + 156 * MBYTE);
  float*  YG    = (float*)(wsb + 160 * MBYTE);
  float*  YSI   = (float*)(wsb + 176 * MBYTE);
  float*  YSG   = (float*)(wsb + 184 * MBYTE);
  float*  YSCp0 = (float*)(wsb + 192 * MBYTE);   // split-K partials (bias in p0)
  float*  YSCp1 = (float*)(wsb + 200 * MBYTE);
  float*  YSBp0 = (float*)(wsb + 208 * MBYTE);
  float*  YSBp1 = (float*)(wsb + 216 * MBYTE);
  float* L0 = (float*)(wsb + 224 * MBYTE);
  float* L1 = L0 + NTOK * EDIM;
  float* L2 = L1 + NTOK * EDIM;
  float* L3 = L2 + NTOK * EDIM;
  float* L4 = L3 + NTOK * EDIM;
  float* meanp = L4 + NTOK * EDIM;
  float* zbias = meanp + EDIM;         // 2048 zeros (bias for W'/kh1 jobs)
  float* vsc = zbias + GK;
  float* vsb = vsc + HHALF;

  float* dispatch = (float*)d_out;
  float* combine = dispatch + (size_t)NTOK * EDIM * CAPV;
  float* rp = combine + (size_t)NTOK * EDIM * CAPV;
  float* aux = rp + (size_t)NTOK * EDIM;

  hipMemsetAsync(d_out, 0, (size_t)out_size * sizeof(float), stream);
  hipMemsetAsync(meanp, 0, (EDIM + GK + 2 * HHALF) * sizeof(float), stream);

  dim3 blk(256);

  // 1) fused prep: splits + transpose-splits + prebias (one dispatch)
  {
    PrepArgs p;
    p.s[0] = {X, Xh, Xl};
    p.s[1] = {IMG, IMGh, IMGl};
    p.s[2] = {GEN, GENh, GENl};
    p.s[3] = {m_w2, M2h, M2l};
    p.t[0] = {m_w1, Wm1h, Wm1l, HDIM};
    p.t[1] = {g_w1, Wg1h, Wg1l, HDIM};
    p.t[2] = {sc_w1, Wsch, Wscl, HHALF};
    p.t[3] = {sb_w1, Wsbh, Wsbl, HHALF};
    p.t[4] = {si_w1, Wsih, Wsil, HHALF};
    p.t[5] = {sg_w1, Wsgh, Wsgl, HHALF};
    p.pb2 = m_b2;
    p.pW1a = sc_w1; p.pb1a = sc_b1; p.pva = vsc;
    p.pW1b = sb_w1; p.pb1b = sb_b1; p.pvb = vsb;
    prep<<<32832, blk, 0, stream>>>(p);
  }

  // 2) GEMM stage A: 6 independent jobs, exactly 256 blocks (+XCD swizzle)
  {
    GJobsA g;
    g.j[0] = {Xh, Xl, Wm1h, Wm1l, m_b1, nullptr, H1h, H1l, 1, HDIM, 0};      // 64
    g.j[1] = {Xh, Xl, Wg1h, Wg1l, g_b1, YG, nullptr, nullptr, 1, HDIM, 64};  // 64
    g.j[2] = {IMGh, IMGl, Wsih, Wsil, si_b1, YSI, nullptr, nullptr, 1, HHALF, 128}; // 32
    g.j[3] = {GENh, GENl, Wsgh, Wsgl, sg_b1, YSG, nullptr, nullptr, 1, HHALF, 160}; // 32
    g.j[4] = {Wsch, Wscl, M2h, M2l, zbias, nullptr, WPsch, WPscl, 0, HDIM, 192};    // 32 (M=1024)
    g.j[5] = {Wsbh, Wsbl, M2h, M2l, zbias, nullptr, WPsbh, WPsbl, 0, HDIM, 224};    // 32 (M=1024)
    gemm_phased<<<256, dim3(512), 0, stream>>>(g);
  }

  // 3) GEMM stage B': split-K=2 partials (relu deferred), 512 blocks (+swizzle)
  {
    GJobs g;
    g.j[0] = {H1h, H1l, WPsch, WPscl, vsc, YSCp0, nullptr, nullptr, 0, HHALF, 0, 1024};
    g.j[1] = {H1h + 1024, H1l + 1024, WPsch + 1024, WPscl + 1024, zbias, YSCp1,
              nullptr, nullptr, 0, HHALF, 128, 1024};
    g.j[2] = {H1h, H1l, WPsbh, WPsbl, vsb, YSBp0, nullptr, nullptr, 0, HHALF, 256, 1024};
    g.j[3] = {H1h + 1024, H1l + 1024, WPsbh + 1024, WPsbl + 1024, zbias, YSBp1,
              nullptr, nullptr, 0, HHALF, 384, 1024};
    g.njobs = 4;
    gemm_split<<<512, blk, 0, stream>>>(g);
  }

  // 4) batched logits (all 5 routers; sc/sb sum partials + relu)
  {
    LJobs l;
    l.j[0] = {YG, YG, g_w2, g_b2, L0, HDIM, 0};
    l.j[1] = {YSI, YSI, si_w2, si_b2, L1, HHALF, 0};
    l.j[2] = {YSG, YSG, sg_w2, sg_b2, L2, HHALF, 0};
    l.j[3] = {YSCp0, YSCp1, sc_w2, sc_b2, L3, HHALF, 1};
    l.j[4] = {YSBp0, YSBp1, sb_w2, sb_b2, L4, HHALF, 1};
    logits_kernel<<<5 * 256, blk, 0, stream>>>(l);
  }

  // 5) finalize + aux
  finalize_kernel<<<NTOK / 256, blk, 0, stream>>>(L0, L1, L2, L3, L4,
                                                  dispatch, combine, rp, meanp);
  aux_kernel<<<1, 64, 0, stream>>>(meanp, aux);
}